// Round 1
// baseline (465.478 us; speedup 1.0000x reference)
//
#include <hip/hip_runtime.h>
#include <math.h>

// RVQECell on MI355X.
// State: [B=32][2^19] fp32. Lane l <-> state bit (18-l). inout = bits 13..18,
// work = bits 1..12, ancilla = bit 0 (spectator).
//
// R6 changes (vs R5 @ 390 us, main=191 us):
//  (1) main_kernel: 512 threads/block, one batch slot per half-block.
//      Same 64 KiB 2-slot LDS + table layout, but occupancy 8 -> 16 waves/CU
//      (R5 counters: VALUBusy 70%, Occupancy 20% -> issue/latency bound).
//      Table loads duplicated across halves but L1-resident.
//  (2) out_kernel: rewritten through a 64x256 LDS tile (XOR-swizzled,
//      verified conflict-free) -> float4 (1 KiB/wave-inst) global I/O, and
//      per-stage ev[32] staging so the scheduler cannot hoist all 192 table
//      loads (spill protection for a[64]). Defensive: out_kernel never showed
//      in top-5 counters; bench-total arithmetic says it may be ~150 us.

#define BIAS_F 1.57079632679489662f

typedef float v4f __attribute__((ext_vector_type(4)));

__device__ __forceinline__ float4 ntload4(const float* p) {
    v4f v = __builtin_nontemporal_load((const v4f*)p);
    return make_float4(v.x, v.y, v.z, v.w);
}
__device__ __forceinline__ void ntstore4(float* p, float4 f) {
    v4f v = {f.x, f.y, f.z, f.w};
    __builtin_nontemporal_store(v, (v4f*)p);
}

// ---- LDS bank swizzle: fold bits 7..5 into 4..2 (keeps float4 contiguity) ----
__device__ __forceinline__ int SW(int i) { return i ^ ((i >> 3) & 0x1C); }
__device__ __forceinline__ float4 ldsld4(const float* st, int i) {
    return *(const float4*)&st[SW(i)];
}
__device__ __forceinline__ void ldsst4(float* st, int i, float4 v) {
    *(float4*)&st[SW(i)] = v;
}

// decode packed entry: v = c if c<=s (v>=0) else -s
__device__ __forceinline__ float2 dec(float v) {
    float t = sqrtf(fmaf(-v, v, 1.0f));
    float c = v >= 0.f ? v : t;
    float s = v >= 0.f ? t : -v;
    return make_float2(c, s);
}
__device__ __forceinline__ float4 dec4(float2 g) {
    float2 u = dec(g.x), w = dec(g.y);
    return make_float4(u.x, u.y, w.x, w.y);
}
#define LD2(p) (*(const float2*)(p))
#define LD4(p) (*(const float4*)(p))

// rotation on pairs (A.k, B.k); e = (c01,s01,c23,s23); .x/.y share angle (bit0)
__device__ __forceinline__ void rot4(float4& A, float4& B, float4 e) {
    float ax = A.x, ay = A.y, az = A.z, aw = A.w;
    A.x = e.x * ax - e.y * B.x;  B.x = e.y * ax + e.x * B.x;
    A.y = e.x * ay - e.y * B.y;  B.y = e.y * ay + e.x * B.y;
    A.z = e.z * az - e.w * B.z;  B.z = e.w * az + e.z * B.z;
    A.w = e.z * aw - e.w * B.w;  B.w = e.w * aw + e.z * B.w;
}
// rotation within a quad: pairs (x,z),(y,w)  (target = amp bit 1)
__device__ __forceinline__ void rotq(float4& P, float c, float s) {
    float px = P.x, py = P.y;
    P.x = c * px - s * P.z;  P.z = s * px + c * P.z;
    P.y = c * py - s * P.w;  P.w = s * py + c * P.w;
}

// ============================ K1: tables ============================
__global__ __launch_bounds__(256) void tables_kernel(
    const float* __restrict__ w_in1, const float* __restrict__ w_in2,
    const float* __restrict__ w_k1,  const float* __restrict__ w_k2,
    const float* __restrict__ w_out1, const float* __restrict__ w_out2,
    float* __restrict__ tab)
{
    const int n = blockIdx.y;
    const int hi = blockIdx.x;       // x bits 16..8
    const int tid = threadIdx.x;     // x bits 7..0
    const float* th1;
    const float* th2;
    if (n < 12)      { th1 = w_in1 + n * 17;         th2 = w_in2 + n * 289; }
    else if (n < 48) { th1 = w_k1 + (n - 12) * 17;   th2 = w_k2 + (n - 12) * 289; }
    else             { th1 = w_out1 + (n - 48) * 17; th2 = w_out2 + (n - 48) * 289; }

    float bu[9], bt[8];
#pragma unroll
    for (int i = 0; i < 9; ++i) bu[i] = (float)((hi >> (8 - i)) & 1);
#pragma unroll
    for (int j = 0; j < 8; ++j) bt[j] = (float)((tid >> (7 - j)) & 1);

    float phi = BIAS_F;
#pragma unroll
    for (int i = 0; i < 9; ++i) {
        float acc = th1[i];
#pragma unroll
        for (int j = i + 1; j < 9; ++j) acc += bu[j] * th2[i * 17 + j];
#pragma unroll
        for (int j = 0; j < 8; ++j)     acc += bt[j] * th2[i * 17 + 9 + j];
        phi += bu[i] * acc;
    }
#pragma unroll
    for (int a = 0; a < 8; ++a) {
        float acc = th1[9 + a];
#pragma unroll
        for (int b2 = a + 1; b2 < 8; ++b2) acc += bt[b2] * th2[(9 + a) * 17 + 9 + b2];
        phi += bt[a] * acc;
    }
    float sp, cp;
    sincosf(phi, &sp, &cp);
    float c2 = cp * cp, s2 = sp * sp;
    float d = c2 * c2 + s2 * s2;           // >= 0.25 always
    float r = rsqrtf(d);
    r = r * (1.5f - 0.5f * d * r * r);     // one Newton step
    float ca = c2 * r, sa = s2 * r;        // cos a, sin a in [0,1]
    tab[(size_t)n * 131072 + ((hi << 8) | tid)] = (ca <= sa) ? ca : -sa;
}

// ============================ K2: main fused ============================
// High pass (single slot), targets {PA,PA-1,PA-2}.
template <int PA, bool NEUR>
__device__ __forceinline__ void pass_hi(float* sl, int t8,
    const float* tA, const float* tB, const float* tC,
    float cA, float sA, float cB, float sB, float cC, float sC)
{
    const int lowb = PA - 4;
    const int low = t8 & ((1 << lowb) - 1);
    const int high = t8 >> lowb;
    const int i0 = (high << (PA + 1)) | (low << 2);
    const int x0 = (high << (PA - 1)) | (low << 1);
    const int oa = 1 << PA, ob = oa >> 1, oc = oa >> 2;
    const int dhi = oa >> 2, dlo = oa >> 3;
    float4 ea00, ea01, ea10, ea11, eb00, eb01, eb10, eb11, ec00, ec01, ec10, ec11;
    if (NEUR) {
        ea00 = dec4(LD2(&tA[x0]));        ea01 = dec4(LD2(&tA[x0 + dlo]));
        ea10 = dec4(LD2(&tA[x0 + dhi]));  ea11 = dec4(LD2(&tA[x0 + dhi + dlo]));
        eb00 = dec4(LD2(&tB[x0]));        eb01 = dec4(LD2(&tB[x0 + dlo]));
        eb10 = dec4(LD2(&tB[x0 + dhi]));  eb11 = dec4(LD2(&tB[x0 + dhi + dlo]));
        ec00 = dec4(LD2(&tC[x0]));        ec01 = dec4(LD2(&tC[x0 + dlo]));
        ec10 = dec4(LD2(&tC[x0 + dhi]));  ec11 = dec4(LD2(&tC[x0 + dhi + dlo]));
    } else {
        ea00 = ea01 = ea10 = ea11 = make_float4(cA, sA, cA, sA);
        eb00 = eb01 = eb10 = eb11 = make_float4(cB, sB, cB, sB);
        ec00 = ec01 = ec10 = ec11 = make_float4(cC, sC, cC, sC);
    }
    float4 Q000 = ldsld4(sl, i0),            Q001 = ldsld4(sl, i0 + oc);
    float4 Q010 = ldsld4(sl, i0 + ob),       Q011 = ldsld4(sl, i0 + ob + oc);
    float4 Q100 = ldsld4(sl, i0 + oa),       Q101 = ldsld4(sl, i0 + oa + oc);
    float4 Q110 = ldsld4(sl, i0 + oa + ob),  Q111 = ldsld4(sl, i0 + oa + ob + oc);
    // target PA
    rot4(Q000, Q100, ea00); rot4(Q001, Q101, ea01);
    rot4(Q010, Q110, ea10); rot4(Q011, Q111, ea11);
    // target PA-1
    rot4(Q000, Q010, eb00); rot4(Q001, Q011, eb01);
    rot4(Q100, Q110, eb10); rot4(Q101, Q111, eb11);
    // target PA-2
    rot4(Q000, Q001, ec00); rot4(Q010, Q011, ec01);
    rot4(Q100, Q101, ec10); rot4(Q110, Q111, ec11);
    ldsst4(sl, i0, Q000);            ldsst4(sl, i0 + oc, Q001);
    ldsst4(sl, i0 + ob, Q010);       ldsst4(sl, i0 + ob + oc, Q011);
    ldsst4(sl, i0 + oa, Q100);       ldsst4(sl, i0 + oa + oc, Q101);
    ldsst4(sl, i0 + oa + ob, Q110);  ldsst4(sl, i0 + oa + ob + oc, Q111);
}

// Low pass (single slot), targets {3,2,1}. Thread owns amps i0..i0+31.
template <bool NEUR>
__device__ __forceinline__ void pass_lo(float* sl, int t8,
    const float* tA, const float* tB, const float* tC,
    float cA, float sA, float cB, float sB, float cC, float sC)
{
    const int i0 = t8 << 5, x0 = t8 << 3;
    float4 qa0, qa1, qb0, qb1, qc0, qc1;
    if (NEUR) {
        qa0 = LD4(&tA[x0]); qa1 = LD4(&tA[x0 + 4]);
        qb0 = LD4(&tB[x0]); qb1 = LD4(&tB[x0 + 4]);
        qc0 = LD4(&tC[x0]); qc1 = LD4(&tC[x0 + 4]);
    }
    float4 Q0 = ldsld4(sl, i0),      Q1 = ldsld4(sl, i0 + 4);
    float4 Q2 = ldsld4(sl, i0 + 8),  Q3 = ldsld4(sl, i0 + 12);
    float4 Q4 = ldsld4(sl, i0 + 16), Q5 = ldsld4(sl, i0 + 20);
    float4 Q6 = ldsld4(sl, i0 + 24), Q7 = ldsld4(sl, i0 + 28);
    if (NEUR) {
        // target 3: pairs (k, k+2)
        rot4(Q0, Q2, dec4(make_float2(qa0.x, qa0.y)));
        rot4(Q1, Q3, dec4(make_float2(qa0.z, qa0.w)));
        rot4(Q4, Q6, dec4(make_float2(qa1.x, qa1.y)));
        rot4(Q5, Q7, dec4(make_float2(qa1.z, qa1.w)));
        // target 2: pairs (k, k+1)
        rot4(Q0, Q1, dec4(make_float2(qb0.x, qb0.y)));
        rot4(Q2, Q3, dec4(make_float2(qb0.z, qb0.w)));
        rot4(Q4, Q5, dec4(make_float2(qb1.x, qb1.y)));
        rot4(Q6, Q7, dec4(make_float2(qb1.z, qb1.w)));
        // target 1: in-quad
        { float2 d = dec(qc0.x); rotq(Q0, d.x, d.y); }
        { float2 d = dec(qc0.y); rotq(Q1, d.x, d.y); }
        { float2 d = dec(qc0.z); rotq(Q2, d.x, d.y); }
        { float2 d = dec(qc0.w); rotq(Q3, d.x, d.y); }
        { float2 d = dec(qc1.x); rotq(Q4, d.x, d.y); }
        { float2 d = dec(qc1.y); rotq(Q5, d.x, d.y); }
        { float2 d = dec(qc1.z); rotq(Q6, d.x, d.y); }
        { float2 d = dec(qc1.w); rotq(Q7, d.x, d.y); }
    } else {
        float4 eA = make_float4(cA, sA, cA, sA);
        rot4(Q0, Q2, eA); rot4(Q1, Q3, eA); rot4(Q4, Q6, eA); rot4(Q5, Q7, eA);
        float4 eB = make_float4(cB, sB, cB, sB);
        rot4(Q0, Q1, eB); rot4(Q2, Q3, eB); rot4(Q4, Q5, eB); rot4(Q6, Q7, eB);
        rotq(Q0, cC, sC); rotq(Q1, cC, sC); rotq(Q2, cC, sC); rotq(Q3, cC, sC);
        rotq(Q4, cC, sC); rotq(Q5, cC, sC); rotq(Q6, cC, sC); rotq(Q7, cC, sC);
    }
    ldsst4(sl, i0, Q0);      ldsst4(sl, i0 + 4, Q1);
    ldsst4(sl, i0 + 8, Q2);  ldsst4(sl, i0 + 12, Q3);
    ldsst4(sl, i0 + 16, Q4); ldsst4(sl, i0 + 20, Q5);
    ldsst4(sl, i0 + 24, Q6); ldsst4(sl, i0 + 28, Q7);
}

// 512 threads: half-block per batch slot. 64 KiB LDS -> 2 blocks/CU = 16
// waves/CU (4/SIMD), double the R5 occupancy. VGPR cap 128 via bounds.
__global__ __launch_bounds__(512, 4) void main_kernel(
    const float* __restrict__ batch, const float* __restrict__ w_u,
    const int* __restrict__ inputs, const float* __restrict__ tab,
    float* __restrict__ psi, float* __restrict__ probs)
{
    __shared__ __align__(16) float lds[2][8192];   // 64 KiB: 2 batch slots
    const int tid = threadIdx.x;
    const int t8 = tid & 255;
    const int slot = tid >> 8;                      // wave-uniform
    const int blk = blockIdx.x;
    const int xcd = blk & 7;
    const int vt = (xcd << 3) | ((blk >> 3) & 7);   // table inout value
    const int pair = blk >> 6;                      // 0..15

    if (blk == 0) {   // zero probs for out_kernel atomics (512*4 = 2048)
        float4 z = make_float4(0.f, 0.f, 0.f, 0.f);
        *(float4*)&probs[tid * 4] = z;
    }

    const int b = pair * 2 + slot;
    int fb = 0;
#pragma unroll
    for (int i = 0; i < 6; ++i) fb |= (inputs[b * 6 + i] & 1) << (5 - i);
    const int u = vt ^ fb;
    float* sl = lds[slot];
    {
        const float* src = batch + ((size_t)b << 19) + ((size_t)u << 13);
#pragma unroll
        for (int k = 0; k < 8; ++k) {
            int i4 = (k * 256 + t8) * 4;
            float4 v = ntload4(&src[i4]);
            *(float4*)&sl[SW(i4)] = v;
        }
    }

    const float* tb = tab + (vt << 11);
#define TN(j) (tb + (size_t)(j) * 131072)
#define BAR __syncthreads()
    BAR;
    // ---- input layer (neurons 0..11, target bit 12-j) ----
    pass_hi<12, true>(sl, t8, TN(0), TN(1), TN(2), 0,0,0,0,0,0);  BAR;
    pass_hi<9,  true>(sl, t8, TN(3), TN(4), TN(5), 0,0,0,0,0,0);  BAR;
    pass_hi<6,  true>(sl, t8, TN(6), TN(7), TN(8), 0,0,0,0,0,0);  BAR;
    pass_lo<true>(sl, t8, TN(9), TN(10), TN(11), 0,0,0,0,0,0);    BAR;

#pragma unroll 1
    for (int st2 = 0; st2 < 3; ++st2) {
        const float* wu = w_u + st2 * 12;
        float c0, s0, c1, s1, c2, s2;
        sincosf(wu[0], &s0, &c0); sincosf(wu[1], &s1, &c1); sincosf(wu[2], &s2, &c2);
        pass_hi<12, false>(sl, t8, 0,0,0, c0,s0, c1,s1, c2,s2);   BAR;
        sincosf(wu[3], &s0, &c0); sincosf(wu[4], &s1, &c1); sincosf(wu[5], &s2, &c2);
        pass_hi<9, false>(sl, t8, 0,0,0, c0,s0, c1,s1, c2,s2);    BAR;
        sincosf(wu[6], &s0, &c0); sincosf(wu[7], &s1, &c1); sincosf(wu[8], &s2, &c2);
        pass_hi<6, false>(sl, t8, 0,0,0, c0,s0, c1,s1, c2,s2);    BAR;
        sincosf(wu[9], &s0, &c0); sincosf(wu[10], &s1, &c1); sincosf(wu[11], &s2, &c2);
        pass_lo<false>(sl, t8, 0,0,0, c0,s0, c1,s1, c2,s2);       BAR;

        const int nb = 12 + st2 * 12;
        pass_hi<12, true>(sl, t8, TN(nb+0), TN(nb+1), TN(nb+2), 0,0,0,0,0,0); BAR;
        pass_hi<9,  true>(sl, t8, TN(nb+3), TN(nb+4), TN(nb+5), 0,0,0,0,0,0); BAR;
        pass_hi<6,  true>(sl, t8, TN(nb+6), TN(nb+7), TN(nb+8), 0,0,0,0,0,0); BAR;
        pass_lo<true>(sl, t8, TN(nb+9), TN(nb+10), TN(nb+11), 0,0,0,0,0,0);   BAR;
    }
#undef TN
#undef BAR

    {
        float* dst = psi + ((size_t)b << 19) + ((size_t)u << 13);
#pragma unroll
        for (int k = 0; k < 8; ++k) {
            int i4 = (k * 256 + t8) * 4;
            float4 v = *(const float4*)&sl[SW(i4)];
            ntstore4(&dst[i4], v);
        }
    }
}

// ============================ K3: output layer + probs ============================
// Tile 64 k x 256 cols through LDS. Tile word = k*256 + (c ^ ((k&15)<<2)):
//  - row float4 I/O (1 KiB/wave-inst, conflict-free b128),
//  - column b32 reads/writes: bank = (t ^ ((k&15)<<2))&31, permutation -> free,
//  - reduction: lane k reads c = seg*64+((j+k)&63); banks verified all-distinct.
__global__ __launch_bounds__(256, 2) void out_kernel(
    const float* __restrict__ tab, float* __restrict__ psi,
    float* __restrict__ probs)
{
    __shared__ __align__(16) float ts[16384];   // 64 KiB tile
    const int tid = threadIdx.x;
    const int lane = tid & 63;
    const int wv = tid >> 6;
    const int b = blockIdx.x >> 5;
    const int c0 = (blockIdx.x & 31) << 8;
    float* gbase = psi + ((size_t)b << 19) + c0;

    // ---- load: wave wv loads rows wv*16..wv*16+15, lane l -> cols 4l..4l+3 ----
#pragma unroll
    for (int i = 0; i < 16; ++i) {
        int k = wv * 16 + i;
        float4 v = ntload4(&gbase[((size_t)k << 13) + lane * 4]);
        int f4 = lane ^ (k & 15);
        *(float4*)&ts[k * 256 + f4 * 4] = v;
    }
    __syncthreads();

    // ---- column phase: thread owns col c = tid ----
    float a[64];
#pragma unroll
    for (int k = 0; k < 64; ++k) a[k] = ts[k * 256 + (tid ^ ((k & 15) << 2))];
    const int w12 = (c0 | tid) >> 1;

#define OSTAGE(J) { \
    const float* tj = tab + (size_t)(48 + (J)) * 131072 + w12; \
    float ev[32]; \
    _Pragma("unroll") \
    for (int m = 0; m < 32; ++m) ev[m] = tj[(size_t)m << 12]; \
    _Pragma("unroll") \
    for (int m = 0; m < 32; ++m) { \
        const int q = 5 - (J); \
        const int k0 = ((m >> q) << (q + 1)) | (m & ((1 << q) - 1)); \
        const int k1 = k0 | (1 << q); \
        float2 e = dec(ev[m]); \
        float A0 = a[k0], A1 = a[k1]; \
        a[k0] = e.x * A0 - e.y * A1; \
        a[k1] = e.y * A0 + e.x * A1; } }
    OSTAGE(0) OSTAGE(1) OSTAGE(2) OSTAGE(3) OSTAGE(4) OSTAGE(5)
#undef OSTAGE

#pragma unroll
    for (int k = 0; k < 64; ++k) ts[k * 256 + (tid ^ ((k & 15) << 2))] = a[k];
    __syncthreads();

    // ---- store rows back (float4) ----
#pragma unroll
    for (int i = 0; i < 16; ++i) {
        int k = wv * 16 + i;
        int f4 = lane ^ (k & 15);
        float4 v = *(const float4*)&ts[k * 256 + f4 * 4];
        ntstore4(&gbase[((size_t)k << 13) + lane * 4], v);
    }

    // ---- probs: thread (seg=tid>>6, k=tid&63) sums 64 cols, rotated start ----
    const int k6 = tid & 63, seg = tid >> 6;
    float p = 0.f;
#pragma unroll
    for (int j = 0; j < 64; ++j) {
        int c = seg * 64 + ((j + k6) & 63);
        float v = ts[k6 * 256 + (c ^ ((k6 & 15) << 2))];
        p += v * v;
    }
    atomicAdd(&probs[b * 64 + k6], p);
}

// ============================ launch ============================
extern "C" void kernel_launch(void* const* d_in, const int* in_sizes, int n_in,
                              void* d_out, int out_size, void* d_ws, size_t ws_size,
                              hipStream_t stream)
{
    const float* batch  = (const float*)d_in[0];
    const float* w_in1  = (const float*)d_in[1];
    const float* w_in2  = (const float*)d_in[2];
    const float* w_u    = (const float*)d_in[3];
    const float* w_k1   = (const float*)d_in[4];
    const float* w_k2   = (const float*)d_in[5];
    const float* w_out1 = (const float*)d_in[6];
    const float* w_out2 = (const float*)d_in[7];
    const int*   inputs = (const int*)d_in[8];
    float* probs = (float*)d_out;
    float* psi   = (float*)d_out + 2048;      // 32*64 probs, then 32*2^19 psi
    float* tab   = (float*)d_ws;              // 54 * 131072 * 4B = 27 MiB packed

    tables_kernel<<<dim3(512, 54), 256, 0, stream>>>(w_in1, w_in2, w_k1, w_k2,
                                                     w_out1, w_out2, tab);
    main_kernel<<<1024, 512, 0, stream>>>(batch, w_u, inputs, tab, psi, probs);
    out_kernel<<<1024, 256, 0, stream>>>(tab, psi, probs);
}

// Round 2
// 459.163 us; speedup vs baseline: 1.0138x; 1.0138x over previous
//
#include <hip/hip_runtime.h>
#include <math.h>

// RVQECell on MI355X.
// State: [B=32][2^19] fp32. Lane l <-> state bit (18-l). inout = bits 13..18,
// work = bits 1..12, ancilla = bit 0 (spectator).
//
// R7 (vs R6 @ 465 us, main=276 us; R5 @ 390 us, main=191 us):
//  R6 post-mortem: __launch_bounds__(512,4) capped VGPR at 64 -> scratch
//  spills (+180 MB fetch AND write, VGPR_Count 64). Occupancy lever was right
//  (VALUBusy rose), register budget was wrong.
//  R7: 1 batch slot per block, 32 KiB LDS, 256 threads, 2048 blocks,
//  __launch_bounds__(256,4): 4 blocks/CU (LDS 128<=160 KiB), VGPR cap 128
//  (this pass code measured 104 in R5 -> no spill), 16 waves/CU.
//  vt = blk&63 keeps vt&7 == blk&7 == XCD -> same table L2 locality as R5.

#define BIAS_F 1.57079632679489662f

typedef float v4f __attribute__((ext_vector_type(4)));

__device__ __forceinline__ float4 ntload4(const float* p) {
    v4f v = __builtin_nontemporal_load((const v4f*)p);
    return make_float4(v.x, v.y, v.z, v.w);
}
__device__ __forceinline__ void ntstore4(float* p, float4 f) {
    v4f v = {f.x, f.y, f.z, f.w};
    __builtin_nontemporal_store(v, (v4f*)p);
}

// ---- LDS bank swizzle: fold bits 7..5 into 4..2 (keeps float4 contiguity) ----
__device__ __forceinline__ int SW(int i) { return i ^ ((i >> 3) & 0x1C); }
__device__ __forceinline__ float4 ldsld4(const float* st, int i) {
    return *(const float4*)&st[SW(i)];
}
__device__ __forceinline__ void ldsst4(float* st, int i, float4 v) {
    *(float4*)&st[SW(i)] = v;
}

// decode packed entry: v = c if c<=s (v>=0) else -s
__device__ __forceinline__ float2 dec(float v) {
    float t = sqrtf(fmaf(-v, v, 1.0f));
    float c = v >= 0.f ? v : t;
    float s = v >= 0.f ? t : -v;
    return make_float2(c, s);
}
__device__ __forceinline__ float4 dec4(float2 g) {
    float2 u = dec(g.x), w = dec(g.y);
    return make_float4(u.x, u.y, w.x, w.y);
}
#define LD2(p) (*(const float2*)(p))
#define LD4(p) (*(const float4*)(p))

// rotation on pairs (A.k, B.k); e = (c01,s01,c23,s23); .x/.y share angle (bit0)
__device__ __forceinline__ void rot4(float4& A, float4& B, float4 e) {
    float ax = A.x, ay = A.y, az = A.z, aw = A.w;
    A.x = e.x * ax - e.y * B.x;  B.x = e.y * ax + e.x * B.x;
    A.y = e.x * ay - e.y * B.y;  B.y = e.y * ay + e.x * B.y;
    A.z = e.z * az - e.w * B.z;  B.z = e.w * az + e.z * B.z;
    A.w = e.z * aw - e.w * B.w;  B.w = e.w * aw + e.z * B.w;
}
// rotation within a quad: pairs (x,z),(y,w)  (target = amp bit 1)
__device__ __forceinline__ void rotq(float4& P, float c, float s) {
    float px = P.x, py = P.y;
    P.x = c * px - s * P.z;  P.z = s * px + c * P.z;
    P.y = c * py - s * P.w;  P.w = s * py + c * P.w;
}

// ============================ K1: tables ============================
__global__ __launch_bounds__(256) void tables_kernel(
    const float* __restrict__ w_in1, const float* __restrict__ w_in2,
    const float* __restrict__ w_k1,  const float* __restrict__ w_k2,
    const float* __restrict__ w_out1, const float* __restrict__ w_out2,
    float* __restrict__ tab)
{
    const int n = blockIdx.y;
    const int hi = blockIdx.x;       // x bits 16..8
    const int tid = threadIdx.x;     // x bits 7..0
    const float* th1;
    const float* th2;
    if (n < 12)      { th1 = w_in1 + n * 17;         th2 = w_in2 + n * 289; }
    else if (n < 48) { th1 = w_k1 + (n - 12) * 17;   th2 = w_k2 + (n - 12) * 289; }
    else             { th1 = w_out1 + (n - 48) * 17; th2 = w_out2 + (n - 48) * 289; }

    float bu[9], bt[8];
#pragma unroll
    for (int i = 0; i < 9; ++i) bu[i] = (float)((hi >> (8 - i)) & 1);
#pragma unroll
    for (int j = 0; j < 8; ++j) bt[j] = (float)((tid >> (7 - j)) & 1);

    float phi = BIAS_F;
#pragma unroll
    for (int i = 0; i < 9; ++i) {
        float acc = th1[i];
#pragma unroll
        for (int j = i + 1; j < 9; ++j) acc += bu[j] * th2[i * 17 + j];
#pragma unroll
        for (int j = 0; j < 8; ++j)     acc += bt[j] * th2[i * 17 + 9 + j];
        phi += bu[i] * acc;
    }
#pragma unroll
    for (int a = 0; a < 8; ++a) {
        float acc = th1[9 + a];
#pragma unroll
        for (int b2 = a + 1; b2 < 8; ++b2) acc += bt[b2] * th2[(9 + a) * 17 + 9 + b2];
        phi += bt[a] * acc;
    }
    float sp, cp;
    sincosf(phi, &sp, &cp);
    float c2 = cp * cp, s2 = sp * sp;
    float d = c2 * c2 + s2 * s2;           // >= 0.25 always
    float r = rsqrtf(d);
    r = r * (1.5f - 0.5f * d * r * r);     // one Newton step
    float ca = c2 * r, sa = s2 * r;        // cos a, sin a in [0,1]
    tab[(size_t)n * 131072 + ((hi << 8) | tid)] = (ca <= sa) ? ca : -sa;
}

// ============================ K2: main fused ============================
// High pass (single slot), targets {PA,PA-1,PA-2}. Packed table regs
// (12 float2 = 24 VGPR) decoded per-target to keep peak pressure low.
template <int PA, bool NEUR>
__device__ __forceinline__ void pass_hi(float* sl, int t8,
    const float* tA, const float* tB, const float* tC,
    float cA, float sA, float cB, float sB, float cC, float sC)
{
    const int lowb = PA - 4;
    const int low = t8 & ((1 << lowb) - 1);
    const int high = t8 >> lowb;
    const int i0 = (high << (PA + 1)) | (low << 2);
    const int x0 = (high << (PA - 1)) | (low << 1);
    const int oa = 1 << PA, ob = oa >> 1, oc = oa >> 2;
    const int dhi = oa >> 2, dlo = oa >> 3;
    float2 pa0, pa1, pa2, pa3, pb0, pb1, pb2, pb3, pc0, pc1, pc2, pc3;
    if (NEUR) {
        pa0 = LD2(&tA[x0]);       pa1 = LD2(&tA[x0 + dlo]);
        pa2 = LD2(&tA[x0 + dhi]); pa3 = LD2(&tA[x0 + dhi + dlo]);
        pb0 = LD2(&tB[x0]);       pb1 = LD2(&tB[x0 + dlo]);
        pb2 = LD2(&tB[x0 + dhi]); pb3 = LD2(&tB[x0 + dhi + dlo]);
        pc0 = LD2(&tC[x0]);       pc1 = LD2(&tC[x0 + dlo]);
        pc2 = LD2(&tC[x0 + dhi]); pc3 = LD2(&tC[x0 + dhi + dlo]);
    }
    float4 Q000 = ldsld4(sl, i0),            Q001 = ldsld4(sl, i0 + oc);
    float4 Q010 = ldsld4(sl, i0 + ob),       Q011 = ldsld4(sl, i0 + ob + oc);
    float4 Q100 = ldsld4(sl, i0 + oa),       Q101 = ldsld4(sl, i0 + oa + oc);
    float4 Q110 = ldsld4(sl, i0 + oa + ob),  Q111 = ldsld4(sl, i0 + oa + ob + oc);
    if (NEUR) {
        {   // target PA
            float4 e00 = dec4(pa0), e01 = dec4(pa1), e10 = dec4(pa2), e11 = dec4(pa3);
            rot4(Q000, Q100, e00); rot4(Q001, Q101, e01);
            rot4(Q010, Q110, e10); rot4(Q011, Q111, e11);
        }
        {   // target PA-1
            float4 e00 = dec4(pb0), e01 = dec4(pb1), e10 = dec4(pb2), e11 = dec4(pb3);
            rot4(Q000, Q010, e00); rot4(Q001, Q011, e01);
            rot4(Q100, Q110, e10); rot4(Q101, Q111, e11);
        }
        {   // target PA-2
            float4 e00 = dec4(pc0), e01 = dec4(pc1), e10 = dec4(pc2), e11 = dec4(pc3);
            rot4(Q000, Q001, e00); rot4(Q010, Q011, e01);
            rot4(Q100, Q101, e10); rot4(Q110, Q111, e11);
        }
    } else {
        float4 eA = make_float4(cA, sA, cA, sA);
        rot4(Q000, Q100, eA); rot4(Q001, Q101, eA);
        rot4(Q010, Q110, eA); rot4(Q011, Q111, eA);
        float4 eB = make_float4(cB, sB, cB, sB);
        rot4(Q000, Q010, eB); rot4(Q001, Q011, eB);
        rot4(Q100, Q110, eB); rot4(Q101, Q111, eB);
        float4 eC = make_float4(cC, sC, cC, sC);
        rot4(Q000, Q001, eC); rot4(Q010, Q011, eC);
        rot4(Q100, Q101, eC); rot4(Q110, Q111, eC);
    }
    ldsst4(sl, i0, Q000);            ldsst4(sl, i0 + oc, Q001);
    ldsst4(sl, i0 + ob, Q010);       ldsst4(sl, i0 + ob + oc, Q011);
    ldsst4(sl, i0 + oa, Q100);       ldsst4(sl, i0 + oa + oc, Q101);
    ldsst4(sl, i0 + oa + ob, Q110);  ldsst4(sl, i0 + oa + ob + oc, Q111);
}

// Low pass (single slot), targets {3,2,1}. Thread owns amps i0..i0+31.
template <bool NEUR>
__device__ __forceinline__ void pass_lo(float* sl, int t8,
    const float* tA, const float* tB, const float* tC,
    float cA, float sA, float cB, float sB, float cC, float sC)
{
    const int i0 = t8 << 5, x0 = t8 << 3;
    float4 qa0, qa1, qb0, qb1, qc0, qc1;
    if (NEUR) {
        qa0 = LD4(&tA[x0]); qa1 = LD4(&tA[x0 + 4]);
        qb0 = LD4(&tB[x0]); qb1 = LD4(&tB[x0 + 4]);
        qc0 = LD4(&tC[x0]); qc1 = LD4(&tC[x0 + 4]);
    }
    float4 Q0 = ldsld4(sl, i0),      Q1 = ldsld4(sl, i0 + 4);
    float4 Q2 = ldsld4(sl, i0 + 8),  Q3 = ldsld4(sl, i0 + 12);
    float4 Q4 = ldsld4(sl, i0 + 16), Q5 = ldsld4(sl, i0 + 20);
    float4 Q6 = ldsld4(sl, i0 + 24), Q7 = ldsld4(sl, i0 + 28);
    if (NEUR) {
        // target 3: pairs (k, k+2)
        rot4(Q0, Q2, dec4(make_float2(qa0.x, qa0.y)));
        rot4(Q1, Q3, dec4(make_float2(qa0.z, qa0.w)));
        rot4(Q4, Q6, dec4(make_float2(qa1.x, qa1.y)));
        rot4(Q5, Q7, dec4(make_float2(qa1.z, qa1.w)));
        // target 2: pairs (k, k+1)
        rot4(Q0, Q1, dec4(make_float2(qb0.x, qb0.y)));
        rot4(Q2, Q3, dec4(make_float2(qb0.z, qb0.w)));
        rot4(Q4, Q5, dec4(make_float2(qb1.x, qb1.y)));
        rot4(Q6, Q7, dec4(make_float2(qb1.z, qb1.w)));
        // target 1: in-quad
        { float2 d = dec(qc0.x); rotq(Q0, d.x, d.y); }
        { float2 d = dec(qc0.y); rotq(Q1, d.x, d.y); }
        { float2 d = dec(qc0.z); rotq(Q2, d.x, d.y); }
        { float2 d = dec(qc0.w); rotq(Q3, d.x, d.y); }
        { float2 d = dec(qc1.x); rotq(Q4, d.x, d.y); }
        { float2 d = dec(qc1.y); rotq(Q5, d.x, d.y); }
        { float2 d = dec(qc1.z); rotq(Q6, d.x, d.y); }
        { float2 d = dec(qc1.w); rotq(Q7, d.x, d.y); }
    } else {
        float4 eA = make_float4(cA, sA, cA, sA);
        rot4(Q0, Q2, eA); rot4(Q1, Q3, eA); rot4(Q4, Q6, eA); rot4(Q5, Q7, eA);
        float4 eB = make_float4(cB, sB, cB, sB);
        rot4(Q0, Q1, eB); rot4(Q2, Q3, eB); rot4(Q4, Q5, eB); rot4(Q6, Q7, eB);
        rotq(Q0, cC, sC); rotq(Q1, cC, sC); rotq(Q2, cC, sC); rotq(Q3, cC, sC);
        rotq(Q4, cC, sC); rotq(Q5, cC, sC); rotq(Q6, cC, sC); rotq(Q7, cC, sC);
    }
    ldsst4(sl, i0, Q0);      ldsst4(sl, i0 + 4, Q1);
    ldsst4(sl, i0 + 8, Q2);  ldsst4(sl, i0 + 12, Q3);
    ldsst4(sl, i0 + 16, Q4); ldsst4(sl, i0 + 20, Q5);
    ldsst4(sl, i0 + 24, Q6); ldsst4(sl, i0 + 28, Q7);
}

// 2048 blocks x 256 threads, 1 batch slot (32 KiB LDS) per block.
// 4 blocks/CU (LDS 128 KiB), VGPR cap 128 -> no spill, 16 waves/CU.
__global__ __launch_bounds__(256, 4) void main_kernel(
    const float* __restrict__ batch, const float* __restrict__ w_u,
    const int* __restrict__ inputs, const float* __restrict__ tab,
    float* __restrict__ psi, float* __restrict__ probs)
{
    __shared__ __align__(16) float sl[8192];   // 32 KiB: 1 batch slot
    const int t8 = threadIdx.x;
    const int blk = blockIdx.x;
    const int vt = blk & 63;        // table inout value; vt&7 == blk&7 == XCD
    const int b = blk >> 6;         // batch index 0..31

    if (blk == 0) {   // zero probs for out_kernel atomics
        float4 z = make_float4(0.f, 0.f, 0.f, 0.f);
        *(float4*)&probs[t8 * 8] = z;
        *(float4*)&probs[t8 * 8 + 4] = z;
    }

    int fb = 0;
#pragma unroll
    for (int i = 0; i < 6; ++i) fb |= (inputs[b * 6 + i] & 1) << (5 - i);
    const int u = vt ^ fb;
    {
        const float* src = batch + ((size_t)b << 19) + ((size_t)u << 13);
#pragma unroll
        for (int k = 0; k < 8; ++k) {
            int i4 = (k * 256 + t8) * 4;
            float4 v = ntload4(&src[i4]);
            *(float4*)&sl[SW(i4)] = v;
        }
    }

    const float* tb = tab + (vt << 11);
#define TN(j) (tb + (size_t)(j) * 131072)
#define BAR __syncthreads()
    BAR;
    // ---- input layer (neurons 0..11, target bit 12-j) ----
    pass_hi<12, true>(sl, t8, TN(0), TN(1), TN(2), 0,0,0,0,0,0);  BAR;
    pass_hi<9,  true>(sl, t8, TN(3), TN(4), TN(5), 0,0,0,0,0,0);  BAR;
    pass_hi<6,  true>(sl, t8, TN(6), TN(7), TN(8), 0,0,0,0,0,0);  BAR;
    pass_lo<true>(sl, t8, TN(9), TN(10), TN(11), 0,0,0,0,0,0);    BAR;

#pragma unroll 1
    for (int st2 = 0; st2 < 3; ++st2) {
        const float* wu = w_u + st2 * 12;
        float c0, s0, c1, s1, c2, s2;
        sincosf(wu[0], &s0, &c0); sincosf(wu[1], &s1, &c1); sincosf(wu[2], &s2, &c2);
        pass_hi<12, false>(sl, t8, 0,0,0, c0,s0, c1,s1, c2,s2);   BAR;
        sincosf(wu[3], &s0, &c0); sincosf(wu[4], &s1, &c1); sincosf(wu[5], &s2, &c2);
        pass_hi<9, false>(sl, t8, 0,0,0, c0,s0, c1,s1, c2,s2);    BAR;
        sincosf(wu[6], &s0, &c0); sincosf(wu[7], &s1, &c1); sincosf(wu[8], &s2, &c2);
        pass_hi<6, false>(sl, t8, 0,0,0, c0,s0, c1,s1, c2,s2);    BAR;
        sincosf(wu[9], &s0, &c0); sincosf(wu[10], &s1, &c1); sincosf(wu[11], &s2, &c2);
        pass_lo<false>(sl, t8, 0,0,0, c0,s0, c1,s1, c2,s2);       BAR;

        const int nb = 12 + st2 * 12;
        pass_hi<12, true>(sl, t8, TN(nb+0), TN(nb+1), TN(nb+2), 0,0,0,0,0,0); BAR;
        pass_hi<9,  true>(sl, t8, TN(nb+3), TN(nb+4), TN(nb+5), 0,0,0,0,0,0); BAR;
        pass_hi<6,  true>(sl, t8, TN(nb+6), TN(nb+7), TN(nb+8), 0,0,0,0,0,0); BAR;
        pass_lo<true>(sl, t8, TN(nb+9), TN(nb+10), TN(nb+11), 0,0,0,0,0,0);   BAR;
    }
#undef TN
#undef BAR

    {
        float* dst = psi + ((size_t)b << 19) + ((size_t)u << 13);
#pragma unroll
        for (int k = 0; k < 8; ++k) {
            int i4 = (k * 256 + t8) * 4;
            float4 v = *(const float4*)&sl[SW(i4)];
            ntstore4(&dst[i4], v);
        }
    }
}

// ============================ K3: output layer + probs ============================
// Tile 64 k x 256 cols through LDS. Tile word = k*256 + (c ^ ((k&15)<<2)):
//  - row float4 I/O (1 KiB/wave-inst, conflict-free b128),
//  - column b32 reads/writes: bank = (t ^ ((k&15)<<2))&31, permutation -> free,
//  - reduction: lane k reads c = seg*64+((j+k)&63); banks verified all-distinct.
__global__ __launch_bounds__(256, 2) void out_kernel(
    const float* __restrict__ tab, float* __restrict__ psi,
    float* __restrict__ probs)
{
    __shared__ __align__(16) float ts[16384];   // 64 KiB tile
    const int tid = threadIdx.x;
    const int lane = tid & 63;
    const int wv = tid >> 6;
    const int b = blockIdx.x >> 5;
    const int c0 = (blockIdx.x & 31) << 8;
    float* gbase = psi + ((size_t)b << 19) + c0;

    // ---- load: wave wv loads rows wv*16..wv*16+15, lane l -> cols 4l..4l+3 ----
#pragma unroll
    for (int i = 0; i < 16; ++i) {
        int k = wv * 16 + i;
        float4 v = ntload4(&gbase[((size_t)k << 13) + lane * 4]);
        int f4 = lane ^ (k & 15);
        *(float4*)&ts[k * 256 + f4 * 4] = v;
    }
    __syncthreads();

    // ---- column phase: thread owns col c = tid ----
    float a[64];
#pragma unroll
    for (int k = 0; k < 64; ++k) a[k] = ts[k * 256 + (tid ^ ((k & 15) << 2))];
    const int w12 = (c0 | tid) >> 1;

#define OSTAGE(J) { \
    const float* tj = tab + (size_t)(48 + (J)) * 131072 + w12; \
    float ev[32]; \
    _Pragma("unroll") \
    for (int m = 0; m < 32; ++m) ev[m] = tj[(size_t)m << 12]; \
    _Pragma("unroll") \
    for (int m = 0; m < 32; ++m) { \
        const int q = 5 - (J); \
        const int k0 = ((m >> q) << (q + 1)) | (m & ((1 << q) - 1)); \
        const int k1 = k0 | (1 << q); \
        float2 e = dec(ev[m]); \
        float A0 = a[k0], A1 = a[k1]; \
        a[k0] = e.x * A0 - e.y * A1; \
        a[k1] = e.y * A0 + e.x * A1; } }
    OSTAGE(0) OSTAGE(1) OSTAGE(2) OSTAGE(3) OSTAGE(4) OSTAGE(5)
#undef OSTAGE

#pragma unroll
    for (int k = 0; k < 64; ++k) ts[k * 256 + (tid ^ ((k & 15) << 2))] = a[k];
    __syncthreads();

    // ---- store rows back (float4) ----
#pragma unroll
    for (int i = 0; i < 16; ++i) {
        int k = wv * 16 + i;
        int f4 = lane ^ (k & 15);
        float4 v = *(const float4*)&ts[k * 256 + f4 * 4];
        ntstore4(&gbase[((size_t)k << 13) + lane * 4], v);
    }

    // ---- probs: thread (seg=tid>>6, k=tid&63) sums 64 cols, rotated start ----
    const int k6 = tid & 63, seg = tid >> 6;
    float p = 0.f;
#pragma unroll
    for (int j = 0; j < 64; ++j) {
        int c = seg * 64 + ((j + k6) & 63);
        float v = ts[k6 * 256 + (c ^ ((k6 & 15) << 2))];
        p += v * v;
    }
    atomicAdd(&probs[b * 64 + k6], p);
}

// ============================ launch ============================
extern "C" void kernel_launch(void* const* d_in, const int* in_sizes, int n_in,
                              void* d_out, int out_size, void* d_ws, size_t ws_size,
                              hipStream_t stream)
{
    const float* batch  = (const float*)d_in[0];
    const float* w_in1  = (const float*)d_in[1];
    const float* w_in2  = (const float*)d_in[2];
    const float* w_u    = (const float*)d_in[3];
    const float* w_k1   = (const float*)d_in[4];
    const float* w_k2   = (const float*)d_in[5];
    const float* w_out1 = (const float*)d_in[6];
    const float* w_out2 = (const float*)d_in[7];
    const int*   inputs = (const int*)d_in[8];
    float* probs = (float*)d_out;
    float* psi   = (float*)d_out + 2048;      // 32*64 probs, then 32*2^19 psi
    float* tab   = (float*)d_ws;              // 54 * 131072 * 4B = 27 MiB packed

    tables_kernel<<<dim3(512, 54), 256, 0, stream>>>(w_in1, w_in2, w_k1, w_k2,
                                                     w_out1, w_out2, tab);
    main_kernel<<<2048, 256, 0, stream>>>(batch, w_u, inputs, tab, psi, probs);
    out_kernel<<<1024, 256, 0, stream>>>(tab, psi, probs);
}

// Round 3
// 442.407 us; speedup vs baseline: 1.0521x; 1.0379x over previous
//
#include <hip/hip_runtime.h>
#include <math.h>

// RVQECell on MI355X.
// State: [B=32][2^19] fp32. Lane l <-> state bit (18-l). inout = bits 13..18,
// work = bits 1..12, ancilla = bit 0 (spectator).
//
// R8 (vs R7 @ 459 us, main=262 us; R5 @ 390 us, main=191 us):
//  R7 post-mortem: __launch_bounds__(256,4) STILL produced VGPR=64 + spills
//  (FETCH 267 MB / WRITE 204 MB; same as R6's (512,4)). Empirical compiler
//  rule on this toolchain: second arg 4 -> allocator targets 8 waves/EU
//  (64 VGPR) and spills; second arg 2 -> 104 VGPR, no spill (R5, measured).
//  R8: single-slot 32 KiB structure kept, bounds reverted to (256,2).
//  Residency is resource-set: LDS 32 KiB -> 5 blocks/CU max, VGPR ~104 ->
//  4 waves/SIMD -> 4 blocks/CU = 16 waves/CU. Clean stream at 2x R5 waves.

#define BIAS_F 1.57079632679489662f

typedef float v4f __attribute__((ext_vector_type(4)));

__device__ __forceinline__ float4 ntload4(const float* p) {
    v4f v = __builtin_nontemporal_load((const v4f*)p);
    return make_float4(v.x, v.y, v.z, v.w);
}
__device__ __forceinline__ void ntstore4(float* p, float4 f) {
    v4f v = {f.x, f.y, f.z, f.w};
    __builtin_nontemporal_store(v, (v4f*)p);
}

// ---- LDS bank swizzle: fold bits 7..5 into 4..2 (keeps float4 contiguity) ----
__device__ __forceinline__ int SW(int i) { return i ^ ((i >> 3) & 0x1C); }
__device__ __forceinline__ float4 ldsld4(const float* st, int i) {
    return *(const float4*)&st[SW(i)];
}
__device__ __forceinline__ void ldsst4(float* st, int i, float4 v) {
    *(float4*)&st[SW(i)] = v;
}

// decode packed entry: v = c if c<=s (v>=0) else -s
__device__ __forceinline__ float2 dec(float v) {
    float t = sqrtf(fmaf(-v, v, 1.0f));
    float c = v >= 0.f ? v : t;
    float s = v >= 0.f ? t : -v;
    return make_float2(c, s);
}
__device__ __forceinline__ float4 dec4(float2 g) {
    float2 u = dec(g.x), w = dec(g.y);
    return make_float4(u.x, u.y, w.x, w.y);
}
#define LD2(p) (*(const float2*)(p))
#define LD4(p) (*(const float4*)(p))

// rotation on pairs (A.k, B.k); e = (c01,s01,c23,s23); .x/.y share angle (bit0)
__device__ __forceinline__ void rot4(float4& A, float4& B, float4 e) {
    float ax = A.x, ay = A.y, az = A.z, aw = A.w;
    A.x = e.x * ax - e.y * B.x;  B.x = e.y * ax + e.x * B.x;
    A.y = e.x * ay - e.y * B.y;  B.y = e.y * ay + e.x * B.y;
    A.z = e.z * az - e.w * B.z;  B.z = e.w * az + e.z * B.z;
    A.w = e.z * aw - e.w * B.w;  B.w = e.w * aw + e.z * B.w;
}
// rotation within a quad: pairs (x,z),(y,w)  (target = amp bit 1)
__device__ __forceinline__ void rotq(float4& P, float c, float s) {
    float px = P.x, py = P.y;
    P.x = c * px - s * P.z;  P.z = s * px + c * P.z;
    P.y = c * py - s * P.w;  P.w = s * py + c * P.w;
}

// ============================ K1: tables ============================
__global__ __launch_bounds__(256) void tables_kernel(
    const float* __restrict__ w_in1, const float* __restrict__ w_in2,
    const float* __restrict__ w_k1,  const float* __restrict__ w_k2,
    const float* __restrict__ w_out1, const float* __restrict__ w_out2,
    float* __restrict__ tab)
{
    const int n = blockIdx.y;
    const int hi = blockIdx.x;       // x bits 16..8
    const int tid = threadIdx.x;     // x bits 7..0
    const float* th1;
    const float* th2;
    if (n < 12)      { th1 = w_in1 + n * 17;         th2 = w_in2 + n * 289; }
    else if (n < 48) { th1 = w_k1 + (n - 12) * 17;   th2 = w_k2 + (n - 12) * 289; }
    else             { th1 = w_out1 + (n - 48) * 17; th2 = w_out2 + (n - 48) * 289; }

    float bu[9], bt[8];
#pragma unroll
    for (int i = 0; i < 9; ++i) bu[i] = (float)((hi >> (8 - i)) & 1);
#pragma unroll
    for (int j = 0; j < 8; ++j) bt[j] = (float)((tid >> (7 - j)) & 1);

    float phi = BIAS_F;
#pragma unroll
    for (int i = 0; i < 9; ++i) {
        float acc = th1[i];
#pragma unroll
        for (int j = i + 1; j < 9; ++j) acc += bu[j] * th2[i * 17 + j];
#pragma unroll
        for (int j = 0; j < 8; ++j)     acc += bt[j] * th2[i * 17 + 9 + j];
        phi += bu[i] * acc;
    }
#pragma unroll
    for (int a = 0; a < 8; ++a) {
        float acc = th1[9 + a];
#pragma unroll
        for (int b2 = a + 1; b2 < 8; ++b2) acc += bt[b2] * th2[(9 + a) * 17 + 9 + b2];
        phi += bt[a] * acc;
    }
    float sp, cp;
    sincosf(phi, &sp, &cp);
    float c2 = cp * cp, s2 = sp * sp;
    float d = c2 * c2 + s2 * s2;           // >= 0.25 always
    float r = rsqrtf(d);
    r = r * (1.5f - 0.5f * d * r * r);     // one Newton step
    float ca = c2 * r, sa = s2 * r;        // cos a, sin a in [0,1]
    tab[(size_t)n * 131072 + ((hi << 8) | tid)] = (ca <= sa) ? ca : -sa;
}

// ============================ K2: main fused ============================
// High pass (single slot), targets {PA,PA-1,PA-2}. Packed table regs
// (12 float2 = 24 VGPR) decoded per-target to keep peak pressure low.
template <int PA, bool NEUR>
__device__ __forceinline__ void pass_hi(float* sl, int t8,
    const float* tA, const float* tB, const float* tC,
    float cA, float sA, float cB, float sB, float cC, float sC)
{
    const int lowb = PA - 4;
    const int low = t8 & ((1 << lowb) - 1);
    const int high = t8 >> lowb;
    const int i0 = (high << (PA + 1)) | (low << 2);
    const int x0 = (high << (PA - 1)) | (low << 1);
    const int oa = 1 << PA, ob = oa >> 1, oc = oa >> 2;
    const int dhi = oa >> 2, dlo = oa >> 3;
    float2 pa0, pa1, pa2, pa3, pb0, pb1, pb2, pb3, pc0, pc1, pc2, pc3;
    if (NEUR) {
        pa0 = LD2(&tA[x0]);       pa1 = LD2(&tA[x0 + dlo]);
        pa2 = LD2(&tA[x0 + dhi]); pa3 = LD2(&tA[x0 + dhi + dlo]);
        pb0 = LD2(&tB[x0]);       pb1 = LD2(&tB[x0 + dlo]);
        pb2 = LD2(&tB[x0 + dhi]); pb3 = LD2(&tB[x0 + dhi + dlo]);
        pc0 = LD2(&tC[x0]);       pc1 = LD2(&tC[x0 + dlo]);
        pc2 = LD2(&tC[x0 + dhi]); pc3 = LD2(&tC[x0 + dhi + dlo]);
    }
    float4 Q000 = ldsld4(sl, i0),            Q001 = ldsld4(sl, i0 + oc);
    float4 Q010 = ldsld4(sl, i0 + ob),       Q011 = ldsld4(sl, i0 + ob + oc);
    float4 Q100 = ldsld4(sl, i0 + oa),       Q101 = ldsld4(sl, i0 + oa + oc);
    float4 Q110 = ldsld4(sl, i0 + oa + ob),  Q111 = ldsld4(sl, i0 + oa + ob + oc);
    if (NEUR) {
        {   // target PA
            float4 e00 = dec4(pa0), e01 = dec4(pa1), e10 = dec4(pa2), e11 = dec4(pa3);
            rot4(Q000, Q100, e00); rot4(Q001, Q101, e01);
            rot4(Q010, Q110, e10); rot4(Q011, Q111, e11);
        }
        {   // target PA-1
            float4 e00 = dec4(pb0), e01 = dec4(pb1), e10 = dec4(pb2), e11 = dec4(pb3);
            rot4(Q000, Q010, e00); rot4(Q001, Q011, e01);
            rot4(Q100, Q110, e10); rot4(Q101, Q111, e11);
        }
        {   // target PA-2
            float4 e00 = dec4(pc0), e01 = dec4(pc1), e10 = dec4(pc2), e11 = dec4(pc3);
            rot4(Q000, Q001, e00); rot4(Q010, Q011, e01);
            rot4(Q100, Q101, e10); rot4(Q110, Q111, e11);
        }
    } else {
        float4 eA = make_float4(cA, sA, cA, sA);
        rot4(Q000, Q100, eA); rot4(Q001, Q101, eA);
        rot4(Q010, Q110, eA); rot4(Q011, Q111, eA);
        float4 eB = make_float4(cB, sB, cB, sB);
        rot4(Q000, Q010, eB); rot4(Q001, Q011, eB);
        rot4(Q100, Q110, eB); rot4(Q101, Q111, eB);
        float4 eC = make_float4(cC, sC, cC, sC);
        rot4(Q000, Q001, eC); rot4(Q010, Q011, eC);
        rot4(Q100, Q101, eC); rot4(Q110, Q111, eC);
    }
    ldsst4(sl, i0, Q000);            ldsst4(sl, i0 + oc, Q001);
    ldsst4(sl, i0 + ob, Q010);       ldsst4(sl, i0 + ob + oc, Q011);
    ldsst4(sl, i0 + oa, Q100);       ldsst4(sl, i0 + oa + oc, Q101);
    ldsst4(sl, i0 + oa + ob, Q110);  ldsst4(sl, i0 + oa + ob + oc, Q111);
}

// Low pass (single slot), targets {3,2,1}. Thread owns amps i0..i0+31.
template <bool NEUR>
__device__ __forceinline__ void pass_lo(float* sl, int t8,
    const float* tA, const float* tB, const float* tC,
    float cA, float sA, float cB, float sB, float cC, float sC)
{
    const int i0 = t8 << 5, x0 = t8 << 3;
    float4 qa0, qa1, qb0, qb1, qc0, qc1;
    if (NEUR) {
        qa0 = LD4(&tA[x0]); qa1 = LD4(&tA[x0 + 4]);
        qb0 = LD4(&tB[x0]); qb1 = LD4(&tB[x0 + 4]);
        qc0 = LD4(&tC[x0]); qc1 = LD4(&tC[x0 + 4]);
    }
    float4 Q0 = ldsld4(sl, i0),      Q1 = ldsld4(sl, i0 + 4);
    float4 Q2 = ldsld4(sl, i0 + 8),  Q3 = ldsld4(sl, i0 + 12);
    float4 Q4 = ldsld4(sl, i0 + 16), Q5 = ldsld4(sl, i0 + 20);
    float4 Q6 = ldsld4(sl, i0 + 24), Q7 = ldsld4(sl, i0 + 28);
    if (NEUR) {
        // target 3: pairs (k, k+2)
        rot4(Q0, Q2, dec4(make_float2(qa0.x, qa0.y)));
        rot4(Q1, Q3, dec4(make_float2(qa0.z, qa0.w)));
        rot4(Q4, Q6, dec4(make_float2(qa1.x, qa1.y)));
        rot4(Q5, Q7, dec4(make_float2(qa1.z, qa1.w)));
        // target 2: pairs (k, k+1)
        rot4(Q0, Q1, dec4(make_float2(qb0.x, qb0.y)));
        rot4(Q2, Q3, dec4(make_float2(qb0.z, qb0.w)));
        rot4(Q4, Q5, dec4(make_float2(qb1.x, qb1.y)));
        rot4(Q6, Q7, dec4(make_float2(qb1.z, qb1.w)));
        // target 1: in-quad
        { float2 d = dec(qc0.x); rotq(Q0, d.x, d.y); }
        { float2 d = dec(qc0.y); rotq(Q1, d.x, d.y); }
        { float2 d = dec(qc0.z); rotq(Q2, d.x, d.y); }
        { float2 d = dec(qc0.w); rotq(Q3, d.x, d.y); }
        { float2 d = dec(qc1.x); rotq(Q4, d.x, d.y); }
        { float2 d = dec(qc1.y); rotq(Q5, d.x, d.y); }
        { float2 d = dec(qc1.z); rotq(Q6, d.x, d.y); }
        { float2 d = dec(qc1.w); rotq(Q7, d.x, d.y); }
    } else {
        float4 eA = make_float4(cA, sA, cA, sA);
        rot4(Q0, Q2, eA); rot4(Q1, Q3, eA); rot4(Q4, Q6, eA); rot4(Q5, Q7, eA);
        float4 eB = make_float4(cB, sB, cB, sB);
        rot4(Q0, Q1, eB); rot4(Q2, Q3, eB); rot4(Q4, Q5, eB); rot4(Q6, Q7, eB);
        rotq(Q0, cC, sC); rotq(Q1, cC, sC); rotq(Q2, cC, sC); rotq(Q3, cC, sC);
        rotq(Q4, cC, sC); rotq(Q5, cC, sC); rotq(Q6, cC, sC); rotq(Q7, cC, sC);
    }
    ldsst4(sl, i0, Q0);      ldsst4(sl, i0 + 4, Q1);
    ldsst4(sl, i0 + 8, Q2);  ldsst4(sl, i0 + 12, Q3);
    ldsst4(sl, i0 + 16, Q4); ldsst4(sl, i0 + 20, Q5);
    ldsst4(sl, i0 + 24, Q6); ldsst4(sl, i0 + 28, Q7);
}

// 2048 blocks x 256 threads, 1 batch slot (32 KiB LDS) per block.
// bounds (256,2): compiler allocates ~104 VGPR (measured R5), no spill;
// hardware packs 4 blocks/CU (VGPR-limited) = 16 waves/CU.
__global__ __launch_bounds__(256, 2) void main_kernel(
    const float* __restrict__ batch, const float* __restrict__ w_u,
    const int* __restrict__ inputs, const float* __restrict__ tab,
    float* __restrict__ psi, float* __restrict__ probs)
{
    __shared__ __align__(16) float sl[8192];   // 32 KiB: 1 batch slot
    const int t8 = threadIdx.x;
    const int blk = blockIdx.x;
    const int vt = blk & 63;        // table inout value; vt&7 == blk&7 == XCD
    const int b = blk >> 6;         // batch index 0..31

    if (blk == 0) {   // zero probs for out_kernel atomics
        float4 z = make_float4(0.f, 0.f, 0.f, 0.f);
        *(float4*)&probs[t8 * 8] = z;
        *(float4*)&probs[t8 * 8 + 4] = z;
    }

    int fb = 0;
#pragma unroll
    for (int i = 0; i < 6; ++i) fb |= (inputs[b * 6 + i] & 1) << (5 - i);
    const int u = vt ^ fb;
    {
        const float* src = batch + ((size_t)b << 19) + ((size_t)u << 13);
#pragma unroll
        for (int k = 0; k < 8; ++k) {
            int i4 = (k * 256 + t8) * 4;
            float4 v = ntload4(&src[i4]);
            *(float4*)&sl[SW(i4)] = v;
        }
    }

    const float* tb = tab + (vt << 11);
#define TN(j) (tb + (size_t)(j) * 131072)
#define BAR __syncthreads()
    BAR;
    // ---- input layer (neurons 0..11, target bit 12-j) ----
    pass_hi<12, true>(sl, t8, TN(0), TN(1), TN(2), 0,0,0,0,0,0);  BAR;
    pass_hi<9,  true>(sl, t8, TN(3), TN(4), TN(5), 0,0,0,0,0,0);  BAR;
    pass_hi<6,  true>(sl, t8, TN(6), TN(7), TN(8), 0,0,0,0,0,0);  BAR;
    pass_lo<true>(sl, t8, TN(9), TN(10), TN(11), 0,0,0,0,0,0);    BAR;

#pragma unroll 1
    for (int st2 = 0; st2 < 3; ++st2) {
        const float* wu = w_u + st2 * 12;
        float c0, s0, c1, s1, c2, s2;
        sincosf(wu[0], &s0, &c0); sincosf(wu[1], &s1, &c1); sincosf(wu[2], &s2, &c2);
        pass_hi<12, false>(sl, t8, 0,0,0, c0,s0, c1,s1, c2,s2);   BAR;
        sincosf(wu[3], &s0, &c0); sincosf(wu[4], &s1, &c1); sincosf(wu[5], &s2, &c2);
        pass_hi<9, false>(sl, t8, 0,0,0, c0,s0, c1,s1, c2,s2);    BAR;
        sincosf(wu[6], &s0, &c0); sincosf(wu[7], &s1, &c1); sincosf(wu[8], &s2, &c2);
        pass_hi<6, false>(sl, t8, 0,0,0, c0,s0, c1,s1, c2,s2);    BAR;
        sincosf(wu[9], &s0, &c0); sincosf(wu[10], &s1, &c1); sincosf(wu[11], &s2, &c2);
        pass_lo<false>(sl, t8, 0,0,0, c0,s0, c1,s1, c2,s2);       BAR;

        const int nb = 12 + st2 * 12;
        pass_hi<12, true>(sl, t8, TN(nb+0), TN(nb+1), TN(nb+2), 0,0,0,0,0,0); BAR;
        pass_hi<9,  true>(sl, t8, TN(nb+3), TN(nb+4), TN(nb+5), 0,0,0,0,0,0); BAR;
        pass_hi<6,  true>(sl, t8, TN(nb+6), TN(nb+7), TN(nb+8), 0,0,0,0,0,0); BAR;
        pass_lo<true>(sl, t8, TN(nb+9), TN(nb+10), TN(nb+11), 0,0,0,0,0,0);   BAR;
    }
#undef TN
#undef BAR

    {
        float* dst = psi + ((size_t)b << 19) + ((size_t)u << 13);
#pragma unroll
        for (int k = 0; k < 8; ++k) {
            int i4 = (k * 256 + t8) * 4;
            float4 v = *(const float4*)&sl[SW(i4)];
            ntstore4(&dst[i4], v);
        }
    }
}

// ============================ K3: output layer + probs ============================
// Tile 64 k x 256 cols through LDS. Tile word = k*256 + (c ^ ((k&15)<<2)):
//  - row float4 I/O (1 KiB/wave-inst, conflict-free b128),
//  - column b32 reads/writes: bank = (t ^ ((k&15)<<2))&31, permutation -> free,
//  - reduction: lane k reads c = seg*64+((j+k)&63); banks verified all-distinct.
__global__ __launch_bounds__(256, 2) void out_kernel(
    const float* __restrict__ tab, float* __restrict__ psi,
    float* __restrict__ probs)
{
    __shared__ __align__(16) float ts[16384];   // 64 KiB tile
    const int tid = threadIdx.x;
    const int lane = tid & 63;
    const int wv = tid >> 6;
    const int b = blockIdx.x >> 5;
    const int c0 = (blockIdx.x & 31) << 8;
    float* gbase = psi + ((size_t)b << 19) + c0;

    // ---- load: wave wv loads rows wv*16..wv*16+15, lane l -> cols 4l..4l+3 ----
#pragma unroll
    for (int i = 0; i < 16; ++i) {
        int k = wv * 16 + i;
        float4 v = ntload4(&gbase[((size_t)k << 13) + lane * 4]);
        int f4 = lane ^ (k & 15);
        *(float4*)&ts[k * 256 + f4 * 4] = v;
    }
    __syncthreads();

    // ---- column phase: thread owns col c = tid ----
    float a[64];
#pragma unroll
    for (int k = 0; k < 64; ++k) a[k] = ts[k * 256 + (tid ^ ((k & 15) << 2))];
    const int w12 = (c0 | tid) >> 1;

#define OSTAGE(J) { \
    const float* tj = tab + (size_t)(48 + (J)) * 131072 + w12; \
    float ev[32]; \
    _Pragma("unroll") \
    for (int m = 0; m < 32; ++m) ev[m] = tj[(size_t)m << 12]; \
    _Pragma("unroll") \
    for (int m = 0; m < 32; ++m) { \
        const int q = 5 - (J); \
        const int k0 = ((m >> q) << (q + 1)) | (m & ((1 << q) - 1)); \
        const int k1 = k0 | (1 << q); \
        float2 e = dec(ev[m]); \
        float A0 = a[k0], A1 = a[k1]; \
        a[k0] = e.x * A0 - e.y * A1; \
        a[k1] = e.y * A0 + e.x * A1; } }
    OSTAGE(0) OSTAGE(1) OSTAGE(2) OSTAGE(3) OSTAGE(4) OSTAGE(5)
#undef OSTAGE

#pragma unroll
    for (int k = 0; k < 64; ++k) ts[k * 256 + (tid ^ ((k & 15) << 2))] = a[k];
    __syncthreads();

    // ---- store rows back (float4) ----
#pragma unroll
    for (int i = 0; i < 16; ++i) {
        int k = wv * 16 + i;
        int f4 = lane ^ (k & 15);
        float4 v = *(const float4*)&ts[k * 256 + f4 * 4];
        ntstore4(&gbase[((size_t)k << 13) + lane * 4], v);
    }

    // ---- probs: thread (seg=tid>>6, k=tid&63) sums 64 cols, rotated start ----
    const int k6 = tid & 63, seg = tid >> 6;
    float p = 0.f;
#pragma unroll
    for (int j = 0; j < 64; ++j) {
        int c = seg * 64 + ((j + k6) & 63);
        float v = ts[k6 * 256 + (c ^ ((k6 & 15) << 2))];
        p += v * v;
    }
    atomicAdd(&probs[b * 64 + k6], p);
}

// ============================ launch ============================
extern "C" void kernel_launch(void* const* d_in, const int* in_sizes, int n_in,
                              void* d_out, int out_size, void* d_ws, size_t ws_size,
                              hipStream_t stream)
{
    const float* batch  = (const float*)d_in[0];
    const float* w_in1  = (const float*)d_in[1];
    const float* w_in2  = (const float*)d_in[2];
    const float* w_u    = (const float*)d_in[3];
    const float* w_k1   = (const float*)d_in[4];
    const float* w_k2   = (const float*)d_in[5];
    const float* w_out1 = (const float*)d_in[6];
    const float* w_out2 = (const float*)d_in[7];
    const int*   inputs = (const int*)d_in[8];
    float* probs = (float*)d_out;
    float* psi   = (float*)d_out + 2048;      // 32*64 probs, then 32*2^19 psi
    float* tab   = (float*)d_ws;              // 54 * 131072 * 4B = 27 MiB packed

    tables_kernel<<<dim3(512, 54), 256, 0, stream>>>(w_in1, w_in2, w_k1, w_k2,
                                                     w_out1, w_out2, tab);
    main_kernel<<<2048, 256, 0, stream>>>(batch, w_u, inputs, tab, psi, probs);
    out_kernel<<<1024, 256, 0, stream>>>(tab, psi, probs);
}

// Round 4
// 351.005 us; speedup vs baseline: 1.3261x; 1.2604x over previous
//
#include <hip/hip_runtime.h>
#include <math.h>

// RVQECell on MI355X.
// State: [B=32][2^19] fp32. Lane l <-> state bit (18-l). inout = bits 13..18,
// work = bits 1..12, ancilla = bit 0 (spectator).
//
// R9 (vs R8 @ 442 us, main=253; R5 @ 390, main=191):
//  Evidence across R5-R8: occupancy follows launch_bounds arg2 (2 -> ~20%,
//  4 -> ~40%) and VGPR budget behaves as ~256/EU: this pass (~90+ live regs)
//  cannot exceed 2 waves/EU without spilling. Occupancy lever closed.
//  R9 attacks the VALU floor instead:
//   (a) revert to R5's 2-slot structure (table loads amortized over 2 batch
//       slots + per-thread ILP; R5 measured 191 vs R8 1-slot 253);
//   (b) UNPACK the 48 main-layer tables to float2 (cos,sin) -> the dec()
//       sqrt/Newton decode (~30-35% of the VALU stream) disappears from all
//       neuron passes. Rationale for packing (L2-fill-bound @2.7 TB/s) is
//       obsolete: HBM now at 5% of peak, tables L2/L3-resident.
//   (c) out-layer tables (6) stay packed -> out_kernel regs untouched.
//  Workspace: 48 MiB unpacked + 3 MiB packed = 51 MiB.

#define BIAS_F 1.57079632679489662f

typedef float v4f __attribute__((ext_vector_type(4)));

__device__ __forceinline__ float4 ntload4(const float* p) {
    v4f v = __builtin_nontemporal_load((const v4f*)p);
    return make_float4(v.x, v.y, v.z, v.w);
}
__device__ __forceinline__ void ntstore4(float* p, float4 f) {
    v4f v = {f.x, f.y, f.z, f.w};
    __builtin_nontemporal_store(v, (v4f*)p);
}

// ---- LDS bank swizzle: fold bits 7..5 into 4..2 (keeps float4 contiguity) ----
__device__ __forceinline__ int SW(int i) { return i ^ ((i >> 3) & 0x1C); }
__device__ __forceinline__ float4 ldsld4(const float* st, int i) {
    return *(const float4*)&st[SW(i)];
}
__device__ __forceinline__ void ldsst4(float* st, int i, float4 v) {
    *(float4*)&st[SW(i)] = v;
}

// decode packed entry (out-layer tables only): v = c if c<=s (v>=0) else -s
__device__ __forceinline__ float2 dec(float v) {
    float t = sqrtf(fmaf(-v, v, 1.0f));
    float c = v >= 0.f ? v : t;
    float s = v >= 0.f ? t : -v;
    return make_float2(c, s);
}
#define LD2(p) (*(const float2*)(p))
#define LD4(p) (*(const float4*)(p))

// rotation on pairs (A.k, B.k); e = (c01,s01,c23,s23); .x/.y share angle (bit0)
__device__ __forceinline__ void rot4(float4& A, float4& B, float4 e) {
    float ax = A.x, ay = A.y, az = A.z, aw = A.w;
    A.x = e.x * ax - e.y * B.x;  B.x = e.y * ax + e.x * B.x;
    A.y = e.x * ay - e.y * B.y;  B.y = e.y * ay + e.x * B.y;
    A.z = e.z * az - e.w * B.z;  B.z = e.w * az + e.z * B.z;
    A.w = e.z * aw - e.w * B.w;  B.w = e.w * aw + e.z * B.w;
}
// rotation within a quad: pairs (x,z),(y,w)  (target = amp bit 1)
__device__ __forceinline__ void rotq(float4& P, float c, float s) {
    float px = P.x, py = P.y;
    P.x = c * px - s * P.z;  P.z = s * px + c * P.z;
    P.y = c * py - s * P.w;  P.w = s * py + c * P.w;
}

// Unpacked-table layout: tabu[2*(n*131072 + vt*2048 + x)] = {cos, sin},
// n = 0..47. Packed out tables: tabp[(n-48)*131072 + x], n = 48..53.
#define TABU_FLOATS (48u * 131072u * 2u)   // 12,582,912 floats = 48 MiB

// ============================ K1: tables ============================
__global__ __launch_bounds__(256) void tables_kernel(
    const float* __restrict__ w_in1, const float* __restrict__ w_in2,
    const float* __restrict__ w_k1,  const float* __restrict__ w_k2,
    const float* __restrict__ w_out1, const float* __restrict__ w_out2,
    float* __restrict__ tab)
{
    const int n = blockIdx.y;
    const int hi = blockIdx.x;       // x bits 16..8
    const int tid = threadIdx.x;     // x bits 7..0
    const float* th1;
    const float* th2;
    if (n < 12)      { th1 = w_in1 + n * 17;         th2 = w_in2 + n * 289; }
    else if (n < 48) { th1 = w_k1 + (n - 12) * 17;   th2 = w_k2 + (n - 12) * 289; }
    else             { th1 = w_out1 + (n - 48) * 17; th2 = w_out2 + (n - 48) * 289; }

    float bu[9], bt[8];
#pragma unroll
    for (int i = 0; i < 9; ++i) bu[i] = (float)((hi >> (8 - i)) & 1);
#pragma unroll
    for (int j = 0; j < 8; ++j) bt[j] = (float)((tid >> (7 - j)) & 1);

    float phi = BIAS_F;
#pragma unroll
    for (int i = 0; i < 9; ++i) {
        float acc = th1[i];
#pragma unroll
        for (int j = i + 1; j < 9; ++j) acc += bu[j] * th2[i * 17 + j];
#pragma unroll
        for (int j = 0; j < 8; ++j)     acc += bt[j] * th2[i * 17 + 9 + j];
        phi += bu[i] * acc;
    }
#pragma unroll
    for (int a = 0; a < 8; ++a) {
        float acc = th1[9 + a];
#pragma unroll
        for (int b2 = a + 1; b2 < 8; ++b2) acc += bt[b2] * th2[(9 + a) * 17 + 9 + b2];
        phi += bt[a] * acc;
    }
    float sp, cp;
    sincosf(phi, &sp, &cp);
    float c2 = cp * cp, s2 = sp * sp;
    float d = c2 * c2 + s2 * s2;           // >= 0.25 always
    float r = rsqrtf(d);
    r = r * (1.5f - 0.5f * d * r * r);     // one Newton step
    float ca = c2 * r, sa = s2 * r;        // cos a, sin a in [0,1]
    const int idx = (hi << 8) | tid;
    if (n < 48) {
        float2* p = (float2*)tab + ((size_t)n * 131072 + idx);
        *p = make_float2(ca, sa);
    } else {
        tab[TABU_FLOATS + (size_t)(n - 48) * 131072 + idx] = (ca <= sa) ? ca : -sa;
    }
}

// ============================ K2: main fused ============================
// High pass, targets {PA,PA-1,PA-2}; unpacked (c,s) table regs (12 float4)
// loaded once, reused for both batch slots. t* point at float2 data
// (float-indexed: angle x lives at [2x]).
template <int PA, bool NEUR>
__device__ __forceinline__ void pass_hi2(float* l0, float* l1, int t8,
    const float* tA, const float* tB, const float* tC,
    float cA, float sA, float cB, float sB, float cC, float sC)
{
    const int lowb = PA - 4;
    const int low = t8 & ((1 << lowb) - 1);
    const int high = t8 >> lowb;
    const int i0 = (high << (PA + 1)) | (low << 2);
    const int x0 = (high << (PA - 1)) | (low << 1);
    const int oa = 1 << PA, ob = oa >> 1, oc = oa >> 2;
    const int dhi = oa >> 2, dlo = oa >> 3;
    float4 ea00, ea01, ea10, ea11, eb00, eb01, eb10, eb11, ec00, ec01, ec10, ec11;
    if (NEUR) {
        ea00 = LD4(&tA[2 * x0]);            ea01 = LD4(&tA[2 * (x0 + dlo)]);
        ea10 = LD4(&tA[2 * (x0 + dhi)]);    ea11 = LD4(&tA[2 * (x0 + dhi + dlo)]);
        eb00 = LD4(&tB[2 * x0]);            eb01 = LD4(&tB[2 * (x0 + dlo)]);
        eb10 = LD4(&tB[2 * (x0 + dhi)]);    eb11 = LD4(&tB[2 * (x0 + dhi + dlo)]);
        ec00 = LD4(&tC[2 * x0]);            ec01 = LD4(&tC[2 * (x0 + dlo)]);
        ec10 = LD4(&tC[2 * (x0 + dhi)]);    ec11 = LD4(&tC[2 * (x0 + dhi + dlo)]);
    } else {
        ea00 = ea01 = ea10 = ea11 = make_float4(cA, sA, cA, sA);
        eb00 = eb01 = eb10 = eb11 = make_float4(cB, sB, cB, sB);
        ec00 = ec01 = ec10 = ec11 = make_float4(cC, sC, cC, sC);
    }
#pragma unroll
    for (int s = 0; s < 2; ++s) {
        float* sl = (s == 0) ? l0 : l1;
        float4 Q000 = ldsld4(sl, i0),            Q001 = ldsld4(sl, i0 + oc);
        float4 Q010 = ldsld4(sl, i0 + ob),       Q011 = ldsld4(sl, i0 + ob + oc);
        float4 Q100 = ldsld4(sl, i0 + oa),       Q101 = ldsld4(sl, i0 + oa + oc);
        float4 Q110 = ldsld4(sl, i0 + oa + ob),  Q111 = ldsld4(sl, i0 + oa + ob + oc);
        // target PA
        rot4(Q000, Q100, ea00); rot4(Q001, Q101, ea01);
        rot4(Q010, Q110, ea10); rot4(Q011, Q111, ea11);
        // target PA-1
        rot4(Q000, Q010, eb00); rot4(Q001, Q011, eb01);
        rot4(Q100, Q110, eb10); rot4(Q101, Q111, eb11);
        // target PA-2
        rot4(Q000, Q001, ec00); rot4(Q010, Q011, ec01);
        rot4(Q100, Q101, ec10); rot4(Q110, Q111, ec11);
        ldsst4(sl, i0, Q000);            ldsst4(sl, i0 + oc, Q001);
        ldsst4(sl, i0 + ob, Q010);       ldsst4(sl, i0 + ob + oc, Q011);
        ldsst4(sl, i0 + oa, Q100);       ldsst4(sl, i0 + oa + oc, Q101);
        ldsst4(sl, i0 + oa + ob, Q110);  ldsst4(sl, i0 + oa + ob + oc, Q111);
    }
}

// Low pass, targets {3,2,1}. Thread owns amps i0..i0+31 (8 angles x0..x0+7).
template <bool NEUR>
__device__ __forceinline__ void pass_lo2(float* l0, float* l1, int t8,
    const float* tA, const float* tB, const float* tC,
    float cA, float sA, float cB, float sB, float cC, float sC)
{
    const int i0 = t8 << 5, x0 = t8 << 3;
    float4 ea0, ea1, ea2, ea3, eb0, eb1, eb2, eb3, ec0, ec1, ec2, ec3;
    if (NEUR) {
        ea0 = LD4(&tA[2 * x0]);      ea1 = LD4(&tA[2 * x0 + 4]);
        ea2 = LD4(&tA[2 * x0 + 8]);  ea3 = LD4(&tA[2 * x0 + 12]);
        eb0 = LD4(&tB[2 * x0]);      eb1 = LD4(&tB[2 * x0 + 4]);
        eb2 = LD4(&tB[2 * x0 + 8]);  eb3 = LD4(&tB[2 * x0 + 12]);
        ec0 = LD4(&tC[2 * x0]);      ec1 = LD4(&tC[2 * x0 + 4]);
        ec2 = LD4(&tC[2 * x0 + 8]);  ec3 = LD4(&tC[2 * x0 + 12]);
    } else {
        ea0 = ea1 = ea2 = ea3 = make_float4(cA, sA, cA, sA);
        eb0 = eb1 = eb2 = eb3 = make_float4(cB, sB, cB, sB);
        ec0 = ec1 = ec2 = ec3 = make_float4(cC, sC, cC, sC);
    }
#pragma unroll
    for (int s = 0; s < 2; ++s) {
        float* sl = (s == 0) ? l0 : l1;
        float4 Q0 = ldsld4(sl, i0),      Q1 = ldsld4(sl, i0 + 4);
        float4 Q2 = ldsld4(sl, i0 + 8),  Q3 = ldsld4(sl, i0 + 12);
        float4 Q4 = ldsld4(sl, i0 + 16), Q5 = ldsld4(sl, i0 + 20);
        float4 Q6 = ldsld4(sl, i0 + 24), Q7 = ldsld4(sl, i0 + 28);
        // target 3: pairs (k, k+2)
        rot4(Q0, Q2, ea0); rot4(Q1, Q3, ea1); rot4(Q4, Q6, ea2); rot4(Q5, Q7, ea3);
        // target 2: pairs (k, k+1)
        rot4(Q0, Q1, eb0); rot4(Q2, Q3, eb1); rot4(Q4, Q5, eb2); rot4(Q6, Q7, eb3);
        // target 1: in-quad
        rotq(Q0, ec0.x, ec0.y); rotq(Q1, ec0.z, ec0.w);
        rotq(Q2, ec1.x, ec1.y); rotq(Q3, ec1.z, ec1.w);
        rotq(Q4, ec2.x, ec2.y); rotq(Q5, ec2.z, ec2.w);
        rotq(Q6, ec3.x, ec3.y); rotq(Q7, ec3.z, ec3.w);
        ldsst4(sl, i0, Q0);      ldsst4(sl, i0 + 4, Q1);
        ldsst4(sl, i0 + 8, Q2);  ldsst4(sl, i0 + 12, Q3);
        ldsst4(sl, i0 + 16, Q4); ldsst4(sl, i0 + 20, Q5);
        ldsst4(sl, i0 + 24, Q6); ldsst4(sl, i0 + 28, Q7);
    }
}

__global__ __launch_bounds__(256, 2) void main_kernel(
    const float* __restrict__ batch, const float* __restrict__ w_u,
    const int* __restrict__ inputs, const float* __restrict__ tab,
    float* __restrict__ psi, float* __restrict__ probs)
{
    __shared__ __align__(16) float lds[2][8192];   // 64 KiB: 2 batch slots
    const int t8 = threadIdx.x;
    const int blk = blockIdx.x;
    const int xcd = blk & 7;
    const int vt = (xcd << 3) | ((blk >> 3) & 7);   // table inout value
    const int pair = blk >> 6;                       // 0..15

    if (blk == 0) {   // zero probs for out_kernel atomics
        float4 z = make_float4(0.f, 0.f, 0.f, 0.f);
        *(float4*)&probs[t8 * 8] = z;
        *(float4*)&probs[t8 * 8 + 4] = z;
    }

    int bb[2], uu[2];
#pragma unroll
    for (int s = 0; s < 2; ++s) {
        int b = pair * 2 + s;
        int fb = 0;
#pragma unroll
        for (int i = 0; i < 6; ++i) fb |= (inputs[b * 6 + i] & 1) << (5 - i);
        bb[s] = b; uu[s] = vt ^ fb;
        const float* src = batch + ((size_t)b << 19) + ((size_t)uu[s] << 13);
#pragma unroll
        for (int k = 0; k < 8; ++k) {
            int i4 = (k * 256 + t8) * 4;
            float4 v = ntload4(&src[i4]);
            *(float4*)&lds[s][SW(i4)] = v;
        }
    }
    float* l0 = lds[0];
    float* l1 = lds[1];

    // float2 table base for this vt (float-indexed; angle x at [2x])
    const float* tb = tab + ((size_t)vt << 12);
#define TN(j) (tb + (size_t)(j) * 262144)
#define BAR __syncthreads()
    BAR;
    // ---- input layer (neurons 0..11, target bit 12-j) ----
    pass_hi2<12, true>(l0, l1, t8, TN(0), TN(1), TN(2), 0,0,0,0,0,0);  BAR;
    pass_hi2<9,  true>(l0, l1, t8, TN(3), TN(4), TN(5), 0,0,0,0,0,0);  BAR;
    pass_hi2<6,  true>(l0, l1, t8, TN(6), TN(7), TN(8), 0,0,0,0,0,0);  BAR;
    pass_lo2<true>(l0, l1, t8, TN(9), TN(10), TN(11), 0,0,0,0,0,0);    BAR;

#pragma unroll 1
    for (int st2 = 0; st2 < 3; ++st2) {
        const float* wu = w_u + st2 * 12;
        float c0, s0, c1, s1, c2, s2;
        sincosf(wu[0], &s0, &c0); sincosf(wu[1], &s1, &c1); sincosf(wu[2], &s2, &c2);
        pass_hi2<12, false>(l0, l1, t8, 0,0,0, c0,s0, c1,s1, c2,s2);   BAR;
        sincosf(wu[3], &s0, &c0); sincosf(wu[4], &s1, &c1); sincosf(wu[5], &s2, &c2);
        pass_hi2<9, false>(l0, l1, t8, 0,0,0, c0,s0, c1,s1, c2,s2);    BAR;
        sincosf(wu[6], &s0, &c0); sincosf(wu[7], &s1, &c1); sincosf(wu[8], &s2, &c2);
        pass_hi2<6, false>(l0, l1, t8, 0,0,0, c0,s0, c1,s1, c2,s2);    BAR;
        sincosf(wu[9], &s0, &c0); sincosf(wu[10], &s1, &c1); sincosf(wu[11], &s2, &c2);
        pass_lo2<false>(l0, l1, t8, 0,0,0, c0,s0, c1,s1, c2,s2);       BAR;

        const int nb = 12 + st2 * 12;
        pass_hi2<12, true>(l0, l1, t8, TN(nb+0), TN(nb+1), TN(nb+2), 0,0,0,0,0,0); BAR;
        pass_hi2<9,  true>(l0, l1, t8, TN(nb+3), TN(nb+4), TN(nb+5), 0,0,0,0,0,0); BAR;
        pass_hi2<6,  true>(l0, l1, t8, TN(nb+6), TN(nb+7), TN(nb+8), 0,0,0,0,0,0); BAR;
        pass_lo2<true>(l0, l1, t8, TN(nb+9), TN(nb+10), TN(nb+11), 0,0,0,0,0,0);   BAR;
    }
#undef TN
#undef BAR

#pragma unroll
    for (int s = 0; s < 2; ++s) {
        float* dst = psi + ((size_t)bb[s] << 19) + ((size_t)uu[s] << 13);
#pragma unroll
        for (int k = 0; k < 8; ++k) {
            int i4 = (k * 256 + t8) * 4;
            float4 v = *(const float4*)&lds[s][SW(i4)];
            ntstore4(&dst[i4], v);
        }
    }
}

// ============================ K3: output layer + probs ============================
// Tile 64 k x 256 cols through LDS (XOR-swizzled, conflict-free). Reads the
// PACKED out tables at tab + TABU_FLOATS.
__global__ __launch_bounds__(256, 2) void out_kernel(
    const float* __restrict__ tab, float* __restrict__ psi,
    float* __restrict__ probs)
{
    __shared__ __align__(16) float ts[16384];   // 64 KiB tile
    const int tid = threadIdx.x;
    const int lane = tid & 63;
    const int wv = tid >> 6;
    const int b = blockIdx.x >> 5;
    const int c0 = (blockIdx.x & 31) << 8;
    float* gbase = psi + ((size_t)b << 19) + c0;
    const float* tabp = tab + TABU_FLOATS;

    // ---- load: wave wv loads rows wv*16..wv*16+15, lane l -> cols 4l..4l+3 ----
#pragma unroll
    for (int i = 0; i < 16; ++i) {
        int k = wv * 16 + i;
        float4 v = ntload4(&gbase[((size_t)k << 13) + lane * 4]);
        int f4 = lane ^ (k & 15);
        *(float4*)&ts[k * 256 + f4 * 4] = v;
    }
    __syncthreads();

    // ---- column phase: thread owns col c = tid ----
    float a[64];
#pragma unroll
    for (int k = 0; k < 64; ++k) a[k] = ts[k * 256 + (tid ^ ((k & 15) << 2))];
    const int w12 = (c0 | tid) >> 1;

#define OSTAGE(J) { \
    const float* tj = tabp + (size_t)(J) * 131072 + w12; \
    float ev[32]; \
    _Pragma("unroll") \
    for (int m = 0; m < 32; ++m) ev[m] = tj[(size_t)m << 12]; \
    _Pragma("unroll") \
    for (int m = 0; m < 32; ++m) { \
        const int q = 5 - (J); \
        const int k0 = ((m >> q) << (q + 1)) | (m & ((1 << q) - 1)); \
        const int k1 = k0 | (1 << q); \
        float2 e = dec(ev[m]); \
        float A0 = a[k0], A1 = a[k1]; \
        a[k0] = e.x * A0 - e.y * A1; \
        a[k1] = e.y * A0 + e.x * A1; } }
    OSTAGE(0) OSTAGE(1) OSTAGE(2) OSTAGE(3) OSTAGE(4) OSTAGE(5)
#undef OSTAGE

#pragma unroll
    for (int k = 0; k < 64; ++k) ts[k * 256 + (tid ^ ((k & 15) << 2))] = a[k];
    __syncthreads();

    // ---- store rows back (float4) ----
#pragma unroll
    for (int i = 0; i < 16; ++i) {
        int k = wv * 16 + i;
        int f4 = lane ^ (k & 15);
        float4 v = *(const float4*)&ts[k * 256 + f4 * 4];
        ntstore4(&gbase[((size_t)k << 13) + lane * 4], v);
    }

    // ---- probs: thread (seg=tid>>6, k=tid&63) sums 64 cols, rotated start ----
    const int k6 = tid & 63, seg = tid >> 6;
    float p = 0.f;
#pragma unroll
    for (int j = 0; j < 64; ++j) {
        int c = seg * 64 + ((j + k6) & 63);
        float v = ts[k6 * 256 + (c ^ ((k6 & 15) << 2))];
        p += v * v;
    }
    atomicAdd(&probs[b * 64 + k6], p);
}

// ============================ launch ============================
extern "C" void kernel_launch(void* const* d_in, const int* in_sizes, int n_in,
                              void* d_out, int out_size, void* d_ws, size_t ws_size,
                              hipStream_t stream)
{
    const float* batch  = (const float*)d_in[0];
    const float* w_in1  = (const float*)d_in[1];
    const float* w_in2  = (const float*)d_in[2];
    const float* w_u    = (const float*)d_in[3];
    const float* w_k1   = (const float*)d_in[4];
    const float* w_k2   = (const float*)d_in[5];
    const float* w_out1 = (const float*)d_in[6];
    const float* w_out2 = (const float*)d_in[7];
    const int*   inputs = (const int*)d_in[8];
    float* probs = (float*)d_out;
    float* psi   = (float*)d_out + 2048;      // 32*64 probs, then 32*2^19 psi
    float* tab   = (float*)d_ws;              // 48 MiB float2 + 3 MiB packed

    tables_kernel<<<dim3(512, 54), 256, 0, stream>>>(w_in1, w_in2, w_k1, w_k2,
                                                     w_out1, w_out2, tab);
    main_kernel<<<1024, 256, 0, stream>>>(batch, w_u, inputs, tab, psi, probs);
    out_kernel<<<1024, 256, 0, stream>>>(tab, psi, probs);
}

// Round 5
// 328.264 us; speedup vs baseline: 1.4180x; 1.0693x over previous
//
#include <hip/hip_runtime.h>
#include <math.h>

// RVQECell on MI355X.
// State: [B=32][2^19] fp32. Lane l <-> state bit (18-l). inout = bits 13..18,
// work = bits 1..12, ancilla = bit 0 (spectator).
//
// R10 (vs R9 @ 351 us, main=153):
//  Residual (total - main) has been ~190-200 us for 5 rounds straight ->
//  tables_kernel + out_kernel. Apply the R9 lesson (decode/redundant VALU
//  elimination) to both:
//   (a) ALL 54 tables stored unpacked float2 (54 MiB ws; 51 proven OK).
//       out_kernel's 192 serial dec() sqrt-chains per thread vanish.
//   (b) tables_kernel: hi = blockIdx.x is wave-uniform -> hoist phi_hi and
//       the 9x8 cross-coefficients C[a] into once-per-block uniform code;
//       per-thread work drops ~200 -> ~110 insts (36 FMA + sincos).
//   (c) main_kernel untouched (153 us, VGPR 124, no spill, proven).

#define BIAS_F 1.57079632679489662f

typedef float v4f __attribute__((ext_vector_type(4)));

__device__ __forceinline__ float4 ntload4(const float* p) {
    v4f v = __builtin_nontemporal_load((const v4f*)p);
    return make_float4(v.x, v.y, v.z, v.w);
}
__device__ __forceinline__ void ntstore4(float* p, float4 f) {
    v4f v = {f.x, f.y, f.z, f.w};
    __builtin_nontemporal_store(v, (v4f*)p);
}

// ---- LDS bank swizzle: fold bits 7..5 into 4..2 (keeps float4 contiguity) ----
__device__ __forceinline__ int SW(int i) { return i ^ ((i >> 3) & 0x1C); }
__device__ __forceinline__ float4 ldsld4(const float* st, int i) {
    return *(const float4*)&st[SW(i)];
}
__device__ __forceinline__ void ldsst4(float* st, int i, float4 v) {
    *(float4*)&st[SW(i)] = v;
}

#define LD2(p) (*(const float2*)(p))
#define LD4(p) (*(const float4*)(p))

// rotation on pairs (A.k, B.k); e = (c01,s01,c23,s23); .x/.y share angle (bit0)
__device__ __forceinline__ void rot4(float4& A, float4& B, float4 e) {
    float ax = A.x, ay = A.y, az = A.z, aw = A.w;
    A.x = e.x * ax - e.y * B.x;  B.x = e.y * ax + e.x * B.x;
    A.y = e.x * ay - e.y * B.y;  B.y = e.y * ay + e.x * B.y;
    A.z = e.z * az - e.w * B.z;  B.z = e.w * az + e.z * B.z;
    A.w = e.z * aw - e.w * B.w;  B.w = e.w * aw + e.z * B.w;
}
// rotation within a quad: pairs (x,z),(y,w)  (target = amp bit 1)
__device__ __forceinline__ void rotq(float4& P, float c, float s) {
    float px = P.x, py = P.y;
    P.x = c * px - s * P.z;  P.z = s * px + c * P.z;
    P.y = c * py - s * P.w;  P.w = s * py + c * P.w;
}

// Table layout: float2 tab2[n * 131072 + x] = {cos a, sin a}, n = 0..53.
// n 0..47 = main-layer neurons, 48..53 = out-layer neurons. 54 MiB total.

// ============================ K1: tables ============================
__global__ __launch_bounds__(256) void tables_kernel(
    const float* __restrict__ w_in1, const float* __restrict__ w_in2,
    const float* __restrict__ w_k1,  const float* __restrict__ w_k2,
    const float* __restrict__ w_out1, const float* __restrict__ w_out2,
    float* __restrict__ tab)
{
    const int n = blockIdx.y;
    const int hi = blockIdx.x;       // x bits 16..8 (wave-uniform)
    const int tid = threadIdx.x;     // x bits 7..0
    const float* th1;
    const float* th2;
    if (n < 12)      { th1 = w_in1 + n * 17;         th2 = w_in2 + n * 289; }
    else if (n < 48) { th1 = w_k1 + (n - 12) * 17;   th2 = w_k2 + (n - 12) * 289; }
    else             { th1 = w_out1 + (n - 48) * 17; th2 = w_out2 + (n - 48) * 289; }

    // ---- wave-uniform hi part: phi_hi + cross coefficients C[a] ----
    // (hi is blockIdx.x -> uniform; branches are scalar, adds execute once
    //  per block instead of per-thread-with-bit-weights.)
    float phi_hi = BIAS_F;
    float C[8];
#pragma unroll
    for (int a = 0; a < 8; ++a) C[a] = th1[9 + a];
#pragma unroll
    for (int i = 0; i < 9; ++i) {
        if ((hi >> (8 - i)) & 1) {
            float acc = th1[i];
#pragma unroll
            for (int j = i + 1; j < 9; ++j)
                if ((hi >> (8 - j)) & 1) acc += th2[i * 17 + j];
            phi_hi += acc;
#pragma unroll
            for (int a = 0; a < 8; ++a) C[a] += th2[i * 17 + 9 + a];
        }
    }

    // ---- per-thread lo part: 8 + 28 FMAs ----
    float bt[8];
#pragma unroll
    for (int j = 0; j < 8; ++j) bt[j] = (float)((tid >> (7 - j)) & 1);
    float phi = phi_hi;
#pragma unroll
    for (int a = 0; a < 8; ++a) {
        float acc = C[a];
#pragma unroll
        for (int b2 = a + 1; b2 < 8; ++b2) acc += bt[b2] * th2[(9 + a) * 17 + 9 + b2];
        phi += bt[a] * acc;
    }

    float sp, cp;
    sincosf(phi, &sp, &cp);
    float c2 = cp * cp, s2 = sp * sp;
    float d = c2 * c2 + s2 * s2;           // >= 0.25 always
    float r = rsqrtf(d);
    r = r * (1.5f - 0.5f * d * r * r);     // one Newton step
    float2* dst = (float2*)tab + ((size_t)n * 131072 + (size_t)((hi << 8) | tid));
    *dst = make_float2(c2 * r, s2 * r);    // {cos a, sin a}
}

// ============================ K2: main fused ============================
// High pass, targets {PA,PA-1,PA-2}; unpacked (c,s) table regs (12 float4)
// loaded once, reused for both batch slots. t* point at float2 data
// (float-indexed: angle x lives at [2x]).
template <int PA, bool NEUR>
__device__ __forceinline__ void pass_hi2(float* l0, float* l1, int t8,
    const float* tA, const float* tB, const float* tC,
    float cA, float sA, float cB, float sB, float cC, float sC)
{
    const int lowb = PA - 4;
    const int low = t8 & ((1 << lowb) - 1);
    const int high = t8 >> lowb;
    const int i0 = (high << (PA + 1)) | (low << 2);
    const int x0 = (high << (PA - 1)) | (low << 1);
    const int oa = 1 << PA, ob = oa >> 1, oc = oa >> 2;
    const int dhi = oa >> 2, dlo = oa >> 3;
    float4 ea00, ea01, ea10, ea11, eb00, eb01, eb10, eb11, ec00, ec01, ec10, ec11;
    if (NEUR) {
        ea00 = LD4(&tA[2 * x0]);            ea01 = LD4(&tA[2 * (x0 + dlo)]);
        ea10 = LD4(&tA[2 * (x0 + dhi)]);    ea11 = LD4(&tA[2 * (x0 + dhi + dlo)]);
        eb00 = LD4(&tB[2 * x0]);            eb01 = LD4(&tB[2 * (x0 + dlo)]);
        eb10 = LD4(&tB[2 * (x0 + dhi)]);    eb11 = LD4(&tB[2 * (x0 + dhi + dlo)]);
        ec00 = LD4(&tC[2 * x0]);            ec01 = LD4(&tC[2 * (x0 + dlo)]);
        ec10 = LD4(&tC[2 * (x0 + dhi)]);    ec11 = LD4(&tC[2 * (x0 + dhi + dlo)]);
    } else {
        ea00 = ea01 = ea10 = ea11 = make_float4(cA, sA, cA, sA);
        eb00 = eb01 = eb10 = eb11 = make_float4(cB, sB, cB, sB);
        ec00 = ec01 = ec10 = ec11 = make_float4(cC, sC, cC, sC);
    }
#pragma unroll
    for (int s = 0; s < 2; ++s) {
        float* sl = (s == 0) ? l0 : l1;
        float4 Q000 = ldsld4(sl, i0),            Q001 = ldsld4(sl, i0 + oc);
        float4 Q010 = ldsld4(sl, i0 + ob),       Q011 = ldsld4(sl, i0 + ob + oc);
        float4 Q100 = ldsld4(sl, i0 + oa),       Q101 = ldsld4(sl, i0 + oa + oc);
        float4 Q110 = ldsld4(sl, i0 + oa + ob),  Q111 = ldsld4(sl, i0 + oa + ob + oc);
        // target PA
        rot4(Q000, Q100, ea00); rot4(Q001, Q101, ea01);
        rot4(Q010, Q110, ea10); rot4(Q011, Q111, ea11);
        // target PA-1
        rot4(Q000, Q010, eb00); rot4(Q001, Q011, eb01);
        rot4(Q100, Q110, eb10); rot4(Q101, Q111, eb11);
        // target PA-2
        rot4(Q000, Q001, ec00); rot4(Q010, Q011, ec01);
        rot4(Q100, Q101, ec10); rot4(Q110, Q111, ec11);
        ldsst4(sl, i0, Q000);            ldsst4(sl, i0 + oc, Q001);
        ldsst4(sl, i0 + ob, Q010);       ldsst4(sl, i0 + ob + oc, Q011);
        ldsst4(sl, i0 + oa, Q100);       ldsst4(sl, i0 + oa + oc, Q101);
        ldsst4(sl, i0 + oa + ob, Q110);  ldsst4(sl, i0 + oa + ob + oc, Q111);
    }
}

// Low pass, targets {3,2,1}. Thread owns amps i0..i0+31 (8 angles x0..x0+7).
template <bool NEUR>
__device__ __forceinline__ void pass_lo2(float* l0, float* l1, int t8,
    const float* tA, const float* tB, const float* tC,
    float cA, float sA, float cB, float sB, float cC, float sC)
{
    const int i0 = t8 << 5, x0 = t8 << 3;
    float4 ea0, ea1, ea2, ea3, eb0, eb1, eb2, eb3, ec0, ec1, ec2, ec3;
    if (NEUR) {
        ea0 = LD4(&tA[2 * x0]);      ea1 = LD4(&tA[2 * x0 + 4]);
        ea2 = LD4(&tA[2 * x0 + 8]);  ea3 = LD4(&tA[2 * x0 + 12]);
        eb0 = LD4(&tB[2 * x0]);      eb1 = LD4(&tB[2 * x0 + 4]);
        eb2 = LD4(&tB[2 * x0 + 8]);  eb3 = LD4(&tB[2 * x0 + 12]);
        ec0 = LD4(&tC[2 * x0]);      ec1 = LD4(&tC[2 * x0 + 4]);
        ec2 = LD4(&tC[2 * x0 + 8]);  ec3 = LD4(&tC[2 * x0 + 12]);
    } else {
        ea0 = ea1 = ea2 = ea3 = make_float4(cA, sA, cA, sA);
        eb0 = eb1 = eb2 = eb3 = make_float4(cB, sB, cB, sB);
        ec0 = ec1 = ec2 = ec3 = make_float4(cC, sC, cC, sC);
    }
#pragma unroll
    for (int s = 0; s < 2; ++s) {
        float* sl = (s == 0) ? l0 : l1;
        float4 Q0 = ldsld4(sl, i0),      Q1 = ldsld4(sl, i0 + 4);
        float4 Q2 = ldsld4(sl, i0 + 8),  Q3 = ldsld4(sl, i0 + 12);
        float4 Q4 = ldsld4(sl, i0 + 16), Q5 = ldsld4(sl, i0 + 20);
        float4 Q6 = ldsld4(sl, i0 + 24), Q7 = ldsld4(sl, i0 + 28);
        // target 3: pairs (k, k+2)
        rot4(Q0, Q2, ea0); rot4(Q1, Q3, ea1); rot4(Q4, Q6, ea2); rot4(Q5, Q7, ea3);
        // target 2: pairs (k, k+1)
        rot4(Q0, Q1, eb0); rot4(Q2, Q3, eb1); rot4(Q4, Q5, eb2); rot4(Q6, Q7, eb3);
        // target 1: in-quad
        rotq(Q0, ec0.x, ec0.y); rotq(Q1, ec0.z, ec0.w);
        rotq(Q2, ec1.x, ec1.y); rotq(Q3, ec1.z, ec1.w);
        rotq(Q4, ec2.x, ec2.y); rotq(Q5, ec2.z, ec2.w);
        rotq(Q6, ec3.x, ec3.y); rotq(Q7, ec3.z, ec3.w);
        ldsst4(sl, i0, Q0);      ldsst4(sl, i0 + 4, Q1);
        ldsst4(sl, i0 + 8, Q2);  ldsst4(sl, i0 + 12, Q3);
        ldsst4(sl, i0 + 16, Q4); ldsst4(sl, i0 + 20, Q5);
        ldsst4(sl, i0 + 24, Q6); ldsst4(sl, i0 + 28, Q7);
    }
}

__global__ __launch_bounds__(256, 2) void main_kernel(
    const float* __restrict__ batch, const float* __restrict__ w_u,
    const int* __restrict__ inputs, const float* __restrict__ tab,
    float* __restrict__ psi, float* __restrict__ probs)
{
    __shared__ __align__(16) float lds[2][8192];   // 64 KiB: 2 batch slots
    const int t8 = threadIdx.x;
    const int blk = blockIdx.x;
    const int xcd = blk & 7;
    const int vt = (xcd << 3) | ((blk >> 3) & 7);   // table inout value
    const int pair = blk >> 6;                       // 0..15

    if (blk == 0) {   // zero probs for out_kernel atomics
        float4 z = make_float4(0.f, 0.f, 0.f, 0.f);
        *(float4*)&probs[t8 * 8] = z;
        *(float4*)&probs[t8 * 8 + 4] = z;
    }

    int bb[2], uu[2];
#pragma unroll
    for (int s = 0; s < 2; ++s) {
        int b = pair * 2 + s;
        int fb = 0;
#pragma unroll
        for (int i = 0; i < 6; ++i) fb |= (inputs[b * 6 + i] & 1) << (5 - i);
        bb[s] = b; uu[s] = vt ^ fb;
        const float* src = batch + ((size_t)b << 19) + ((size_t)uu[s] << 13);
#pragma unroll
        for (int k = 0; k < 8; ++k) {
            int i4 = (k * 256 + t8) * 4;
            float4 v = ntload4(&src[i4]);
            *(float4*)&lds[s][SW(i4)] = v;
        }
    }
    float* l0 = lds[0];
    float* l1 = lds[1];

    // float2 table base for this vt (float-indexed; angle x at [2x])
    const float* tb = tab + ((size_t)vt << 12);
#define TN(j) (tb + (size_t)(j) * 262144)
#define BAR __syncthreads()
    BAR;
    // ---- input layer (neurons 0..11, target bit 12-j) ----
    pass_hi2<12, true>(l0, l1, t8, TN(0), TN(1), TN(2), 0,0,0,0,0,0);  BAR;
    pass_hi2<9,  true>(l0, l1, t8, TN(3), TN(4), TN(5), 0,0,0,0,0,0);  BAR;
    pass_hi2<6,  true>(l0, l1, t8, TN(6), TN(7), TN(8), 0,0,0,0,0,0);  BAR;
    pass_lo2<true>(l0, l1, t8, TN(9), TN(10), TN(11), 0,0,0,0,0,0);    BAR;

#pragma unroll 1
    for (int st2 = 0; st2 < 3; ++st2) {
        const float* wu = w_u + st2 * 12;
        float c0, s0, c1, s1, c2, s2;
        sincosf(wu[0], &s0, &c0); sincosf(wu[1], &s1, &c1); sincosf(wu[2], &s2, &c2);
        pass_hi2<12, false>(l0, l1, t8, 0,0,0, c0,s0, c1,s1, c2,s2);   BAR;
        sincosf(wu[3], &s0, &c0); sincosf(wu[4], &s1, &c1); sincosf(wu[5], &s2, &c2);
        pass_hi2<9, false>(l0, l1, t8, 0,0,0, c0,s0, c1,s1, c2,s2);    BAR;
        sincosf(wu[6], &s0, &c0); sincosf(wu[7], &s1, &c1); sincosf(wu[8], &s2, &c2);
        pass_hi2<6, false>(l0, l1, t8, 0,0,0, c0,s0, c1,s1, c2,s2);    BAR;
        sincosf(wu[9], &s0, &c0); sincosf(wu[10], &s1, &c1); sincosf(wu[11], &s2, &c2);
        pass_lo2<false>(l0, l1, t8, 0,0,0, c0,s0, c1,s1, c2,s2);       BAR;

        const int nb = 12 + st2 * 12;
        pass_hi2<12, true>(l0, l1, t8, TN(nb+0), TN(nb+1), TN(nb+2), 0,0,0,0,0,0); BAR;
        pass_hi2<9,  true>(l0, l1, t8, TN(nb+3), TN(nb+4), TN(nb+5), 0,0,0,0,0,0); BAR;
        pass_hi2<6,  true>(l0, l1, t8, TN(nb+6), TN(nb+7), TN(nb+8), 0,0,0,0,0,0); BAR;
        pass_lo2<true>(l0, l1, t8, TN(nb+9), TN(nb+10), TN(nb+11), 0,0,0,0,0,0);   BAR;
    }
#undef TN
#undef BAR

#pragma unroll
    for (int s = 0; s < 2; ++s) {
        float* dst = psi + ((size_t)bb[s] << 19) + ((size_t)uu[s] << 13);
#pragma unroll
        for (int k = 0; k < 8; ++k) {
            int i4 = (k * 256 + t8) * 4;
            float4 v = *(const float4*)&lds[s][SW(i4)];
            ntstore4(&dst[i4], v);
        }
    }
}

// ============================ K3: output layer + probs ============================
// Tile 64 k x 256 cols through LDS (XOR-swizzled, conflict-free). Tables are
// unpacked float2 -> no dec() in the butterfly chain. ev staged 16-at-a-time
// to bound load hoisting (a[64] + 32 ev regs ~ 110 < 128).
__global__ __launch_bounds__(256, 2) void out_kernel(
    const float* __restrict__ tab, float* __restrict__ psi,
    float* __restrict__ probs)
{
    __shared__ __align__(16) float ts[16384];   // 64 KiB tile
    const int tid = threadIdx.x;
    const int lane = tid & 63;
    const int wv = tid >> 6;
    const int b = blockIdx.x >> 5;
    const int c0 = (blockIdx.x & 31) << 8;
    float* gbase = psi + ((size_t)b << 19) + c0;

    // ---- load: wave wv loads rows wv*16..wv*16+15, lane l -> cols 4l..4l+3 ----
#pragma unroll
    for (int i = 0; i < 16; ++i) {
        int k = wv * 16 + i;
        float4 v = ntload4(&gbase[((size_t)k << 13) + lane * 4]);
        int f4 = lane ^ (k & 15);
        *(float4*)&ts[k * 256 + f4 * 4] = v;
    }
    __syncthreads();

    // ---- column phase: thread owns col c = tid ----
    float a[64];
#pragma unroll
    for (int k = 0; k < 64; ++k) a[k] = ts[k * 256 + (tid ^ ((k & 15) << 2))];
    const int w12 = (c0 | tid) >> 1;

#define OSTAGE(J) { \
    const float* tj = tab + 2u * ((size_t)(48 + (J)) * 131072 + (size_t)w12); \
    _Pragma("unroll") \
    for (int h = 0; h < 2; ++h) { \
        float2 ev[16]; \
        _Pragma("unroll") \
        for (int m = 0; m < 16; ++m) ev[m] = LD2(&tj[(size_t)(h * 16 + m) << 13]); \
        _Pragma("unroll") \
        for (int m = 0; m < 16; ++m) { \
            const int mm = h * 16 + m; \
            const int q = 5 - (J); \
            const int k0 = ((mm >> q) << (q + 1)) | (mm & ((1 << q) - 1)); \
            const int k1 = k0 | (1 << q); \
            float2 e = ev[m]; \
            float A0 = a[k0], A1 = a[k1]; \
            a[k0] = e.x * A0 - e.y * A1; \
            a[k1] = e.y * A0 + e.x * A1; } } }
    OSTAGE(0) OSTAGE(1) OSTAGE(2) OSTAGE(3) OSTAGE(4) OSTAGE(5)
#undef OSTAGE

#pragma unroll
    for (int k = 0; k < 64; ++k) ts[k * 256 + (tid ^ ((k & 15) << 2))] = a[k];
    __syncthreads();

    // ---- store rows back (float4) ----
#pragma unroll
    for (int i = 0; i < 16; ++i) {
        int k = wv * 16 + i;
        int f4 = lane ^ (k & 15);
        float4 v = *(const float4*)&ts[k * 256 + f4 * 4];
        ntstore4(&gbase[((size_t)k << 13) + lane * 4], v);
    }

    // ---- probs: thread (seg=tid>>6, k=tid&63) sums 64 cols, rotated start ----
    const int k6 = tid & 63, seg = tid >> 6;
    float p = 0.f;
#pragma unroll
    for (int j = 0; j < 64; ++j) {
        int c = seg * 64 + ((j + k6) & 63);
        float v = ts[k6 * 256 + (c ^ ((k6 & 15) << 2))];
        p += v * v;
    }
    atomicAdd(&probs[b * 64 + k6], p);
}

// ============================ launch ============================
extern "C" void kernel_launch(void* const* d_in, const int* in_sizes, int n_in,
                              void* d_out, int out_size, void* d_ws, size_t ws_size,
                              hipStream_t stream)
{
    const float* batch  = (const float*)d_in[0];
    const float* w_in1  = (const float*)d_in[1];
    const float* w_in2  = (const float*)d_in[2];
    const float* w_u    = (const float*)d_in[3];
    const float* w_k1   = (const float*)d_in[4];
    const float* w_k2   = (const float*)d_in[5];
    const float* w_out1 = (const float*)d_in[6];
    const float* w_out2 = (const float*)d_in[7];
    const int*   inputs = (const int*)d_in[8];
    float* probs = (float*)d_out;
    float* psi   = (float*)d_out + 2048;      // 32*64 probs, then 32*2^19 psi
    float* tab   = (float*)d_ws;              // 54 tables x 1 MiB float2 = 54 MiB

    tables_kernel<<<dim3(512, 54), 256, 0, stream>>>(w_in1, w_in2, w_k1, w_k2,
                                                     w_out1, w_out2, tab);
    main_kernel<<<1024, 256, 0, stream>>>(batch, w_u, inputs, tab, psi, probs);
    out_kernel<<<1024, 256, 0, stream>>>(tab, psi, probs);
}